// Round 1
// baseline (2394.418 us; speedup 1.0000x reference)
//
#include <hip/hip_runtime.h>
#include <math.h>

#define NN 100000
#define NE 3200000
#define NF 256
#define NH 128
#define NC 40

// ---------------------------------------------------------------------------
// GEMM1: xw[n][f] = sum_k x[n][k] * W0[k][f]
// block = 128 threads (f = tid), 4 nodes per block. N = 100000 = 4*25000 exact.
// x rows read as float4; W0 rows broadcast via L2 (128 KB, fully L2-resident).
// ---------------------------------------------------------------------------
__global__ __launch_bounds__(128) void gemm1_k(const float* __restrict__ x,
                                               const float* __restrict__ W0,
                                               float* __restrict__ xw) {
    const int f = threadIdx.x;
    const int n0 = blockIdx.x * 4;
    const float* xr = x + (size_t)n0 * NF;
    float a0 = 0.f, a1 = 0.f, a2 = 0.f, a3 = 0.f;
#pragma unroll 4
    for (int k = 0; k < NF; k += 4) {
        const float4 v0 = *(const float4*)(xr + k);
        const float4 v1 = *(const float4*)(xr + NF + k);
        const float4 v2 = *(const float4*)(xr + 2 * NF + k);
        const float4 v3 = *(const float4*)(xr + 3 * NF + k);
        const float w0 = W0[(size_t)(k + 0) * NH + f];
        const float w1 = W0[(size_t)(k + 1) * NH + f];
        const float w2 = W0[(size_t)(k + 2) * NH + f];
        const float w3 = W0[(size_t)(k + 3) * NH + f];
        a0 = fmaf(v0.x, w0, a0); a0 = fmaf(v0.y, w1, a0);
        a0 = fmaf(v0.z, w2, a0); a0 = fmaf(v0.w, w3, a0);
        a1 = fmaf(v1.x, w0, a1); a1 = fmaf(v1.y, w1, a1);
        a1 = fmaf(v1.z, w2, a1); a1 = fmaf(v1.w, w3, a1);
        a2 = fmaf(v2.x, w0, a2); a2 = fmaf(v2.y, w1, a2);
        a2 = fmaf(v2.z, w2, a2); a2 = fmaf(v2.w, w3, a2);
        a3 = fmaf(v3.x, w0, a3); a3 = fmaf(v3.y, w1, a3);
        a3 = fmaf(v3.z, w2, a3); a3 = fmaf(v3.w, w3, a3);
    }
    xw[(size_t)(n0 + 0) * NH + f] = a0;
    xw[(size_t)(n0 + 1) * NH + f] = a1;
    xw[(size_t)(n0 + 2) * NH + f] = a2;
    xw[(size_t)(n0 + 3) * NH + f] = a3;
}

// ---------------------------------------------------------------------------
// SpMM1 (atomic scatter): hacc[dst][f] += w[e] * xw[src][f], f in [0,128)
// linear index over E*128; 128 consecutive threads share one edge -> coalesced
// gather read and coalesced atomic region.
// ---------------------------------------------------------------------------
__global__ __launch_bounds__(256) void spmm1_k(const int* __restrict__ esrc,
                                               const int* __restrict__ edst,
                                               const float* __restrict__ ew,
                                               const float* __restrict__ xw,
                                               float* __restrict__ hacc) {
    const unsigned int i = blockIdx.x * 256u + threadIdx.x;  // < E*128 = 409.6M
    const unsigned int e = i >> 7;
    const unsigned int f = i & 127u;
    const int s = esrc[e];
    const int d = edst[e];
    const float val = ew[e] * xw[(size_t)s * NH + f];
    atomicAdd(&hacc[(size_t)d * NH + f], val);
}

// ---------------------------------------------------------------------------
// bias + L2 normalize + ReLU: h2[n][f] = relu( (hacc[n][f]+b0[f]) / max(||row||,eps) )
// one block (128 threads, 2 waves) per node.
// ---------------------------------------------------------------------------
__global__ __launch_bounds__(128) void norm_k(const float* __restrict__ hacc,
                                              const float* __restrict__ b0,
                                              float* __restrict__ h2) {
    const int n = blockIdx.x;
    const int f = threadIdx.x;
    const float v = hacc[(size_t)n * NH + f] + b0[f];
    float s = v * v;
#pragma unroll
    for (int o = 32; o > 0; o >>= 1) s += __shfl_down(s, o, 64);
    __shared__ float wsum[2];
    if ((threadIdx.x & 63) == 0) wsum[threadIdx.x >> 6] = s;
    __syncthreads();
    const float nrm = sqrtf(wsum[0] + wsum[1]);
    const float scale = 1.0f / fmaxf(nrm, 1e-12f);
    h2[(size_t)n * NH + f] = fmaxf(v * scale, 0.0f);
}

// ---------------------------------------------------------------------------
// GEMM2: hw[n][f] = sum_k h2[n][k] * W1[k][f]   (K=128, F=40)
// W1 (20 KB) staged in LDS. block = (40,6) = 240 threads, 6 nodes per block.
// ---------------------------------------------------------------------------
__global__ void gemm2_k(const float* __restrict__ h2,
                        const float* __restrict__ W1,
                        float* __restrict__ hw) {
    __shared__ float sW1[NH * NC];
    const int lt = threadIdx.y * NC + threadIdx.x;  // 0..239
    for (int i = lt; i < NH * NC; i += 240) sW1[i] = W1[i];
    __syncthreads();
    const int n = blockIdx.x * 6 + threadIdx.y;
    if (n >= NN) return;
    const int f = threadIdx.x;
    const float* hr = h2 + (size_t)n * NH;
    float acc = 0.f;
#pragma unroll 4
    for (int k = 0; k < NH; k += 4) {
        const float4 hv = *(const float4*)(hr + k);
        acc = fmaf(hv.x, sW1[(k + 0) * NC + f], acc);
        acc = fmaf(hv.y, sW1[(k + 1) * NC + f], acc);
        acc = fmaf(hv.z, sW1[(k + 2) * NC + f], acc);
        acc = fmaf(hv.w, sW1[(k + 3) * NC + f], acc);
    }
    hw[(size_t)n * NC + f] = acc;
}

// ---------------------------------------------------------------------------
// SpMM2 (atomic scatter): z[dst][f] += w[e] * hw[src][f], f in [0,40)
// ---------------------------------------------------------------------------
__global__ __launch_bounds__(256) void spmm2_k(const int* __restrict__ esrc,
                                               const int* __restrict__ edst,
                                               const float* __restrict__ ew,
                                               const float* __restrict__ hw,
                                               float* __restrict__ z) {
    const unsigned int i = blockIdx.x * 256u + threadIdx.x;  // < E*40 = 128M
    if (i >= (unsigned int)NE * NC) return;
    const unsigned int e = i / NC;       // magic-mul div by 40
    const unsigned int f = i - e * NC;
    const int s = esrc[e];
    const int d = edst[e];
    const float val = ew[e] * hw[(size_t)s * NC + f];
    atomicAdd(&z[(size_t)d * NC + f], val);
}

// ---------------------------------------------------------------------------
// bias + log_softmax in-place on z (d_out). one wave per node, 4 nodes/block.
// ---------------------------------------------------------------------------
__global__ __launch_bounds__(256) void lsm_k(float* __restrict__ z,
                                             const float* __restrict__ b1) {
    const int wave = threadIdx.x >> 6;
    const int lane = threadIdx.x & 63;
    const int n = blockIdx.x * 4 + wave;
    float v = -INFINITY;
    if (lane < NC) v = z[(size_t)n * NC + lane] + b1[lane];
    float m = v;
#pragma unroll
    for (int o = 32; o > 0; o >>= 1) m = fmaxf(m, __shfl_down(m, o, 64));
    m = __shfl(m, 0, 64);
    float ex = (lane < NC) ? expf(v - m) : 0.0f;
#pragma unroll
    for (int o = 32; o > 0; o >>= 1) ex += __shfl_down(ex, o, 64);
    const float lse = logf(__shfl(ex, 0, 64));
    if (lane < NC) z[(size_t)n * NC + lane] = v - m - lse;
}

extern "C" void kernel_launch(void* const* d_in, const int* in_sizes, int n_in,
                              void* d_out, int out_size, void* d_ws, size_t ws_size,
                              hipStream_t stream) {
    const float* x    = (const float*)d_in[0];
    const int*   esrc = (const int*)d_in[1];
    const int*   edst = (const int*)d_in[2];
    const float* ew   = (const float*)d_in[3];
    const float* W0   = (const float*)d_in[4];
    const float* b0   = (const float*)d_in[5];
    const float* W1   = (const float*)d_in[6];
    const float* b1   = (const float*)d_in[7];
    float* out = (float*)d_out;

    float* bufA = (float*)d_ws;                 // N*128 floats: xw, later h2
    float* bufB = bufA + (size_t)NN * NH;       // N*128 floats: hacc, later hw

    // 1. xw = x @ W0
    gemm1_k<<<NN / 4, 128, 0, stream>>>(x, W0, bufA);
    // 2. hacc = 0; hacc[dst] += w * xw[src]
    hipMemsetAsync(bufB, 0, (size_t)NN * NH * sizeof(float), stream);
    spmm1_k<<<(NE * (size_t)NH) / 256, 256, 0, stream>>>(esrc, edst, ew, bufA, bufB);
    // 3. h2 = relu(l2norm(hacc + b0))  -> bufA
    norm_k<<<NN, 128, 0, stream>>>(bufB, b0, bufA);
    // 4. hw = h2 @ W1 -> bufB
    gemm2_k<<<(NN + 5) / 6, dim3(40, 6), 0, stream>>>(bufA, W1, bufB);
    // 5. z = 0 (in d_out); z[dst] += w * hw[src]
    hipMemsetAsync(out, 0, (size_t)NN * NC * sizeof(float), stream);
    spmm2_k<<<((size_t)NE * NC + 255) / 256, 256, 0, stream>>>(esrc, edst, ew, bufB, out);
    // 6. log_softmax(z + b1) in place
    lsm_k<<<NN / 4, 256, 0, stream>>>(out, b1);
}

// Round 2
// 1247.835 us; speedup vs baseline: 1.9189x; 1.9189x over previous
//
#include <hip/hip_runtime.h>
#include <math.h>

#define NN 100000
#define NE 3200000
#define NF 256
#define NH 128
#define NC 40

// ============================ GEMM1 =======================================
// xw[n][f] = sum_k x[n][k] * W0[k][f]; 128 threads (f), 4 nodes/block.
__global__ __launch_bounds__(128) void gemm1_k(const float* __restrict__ x,
                                               const float* __restrict__ W0,
                                               float* __restrict__ xw) {
    const int f = threadIdx.x;
    const int n0 = blockIdx.x * 4;
    const float* xr = x + (size_t)n0 * NF;
    float a0 = 0.f, a1 = 0.f, a2 = 0.f, a3 = 0.f;
#pragma unroll 4
    for (int k = 0; k < NF; k += 4) {
        const float4 v0 = *(const float4*)(xr + k);
        const float4 v1 = *(const float4*)(xr + NF + k);
        const float4 v2 = *(const float4*)(xr + 2 * NF + k);
        const float4 v3 = *(const float4*)(xr + 3 * NF + k);
        const float w0 = W0[(size_t)(k + 0) * NH + f];
        const float w1 = W0[(size_t)(k + 1) * NH + f];
        const float w2 = W0[(size_t)(k + 2) * NH + f];
        const float w3 = W0[(size_t)(k + 3) * NH + f];
        a0 = fmaf(v0.x, w0, a0); a0 = fmaf(v0.y, w1, a0);
        a0 = fmaf(v0.z, w2, a0); a0 = fmaf(v0.w, w3, a0);
        a1 = fmaf(v1.x, w0, a1); a1 = fmaf(v1.y, w1, a1);
        a1 = fmaf(v1.z, w2, a1); a1 = fmaf(v1.w, w3, a1);
        a2 = fmaf(v2.x, w0, a2); a2 = fmaf(v2.y, w1, a2);
        a2 = fmaf(v2.z, w2, a2); a2 = fmaf(v2.w, w3, a2);
        a3 = fmaf(v3.x, w0, a3); a3 = fmaf(v3.y, w1, a3);
        a3 = fmaf(v3.z, w2, a3); a3 = fmaf(v3.w, w3, a3);
    }
    xw[(size_t)(n0 + 0) * NH + f] = a0;
    xw[(size_t)(n0 + 1) * NH + f] = a1;
    xw[(size_t)(n0 + 2) * NH + f] = a2;
    xw[(size_t)(n0 + 3) * NH + f] = a3;
}

// ============================ CSR build ===================================
__global__ __launch_bounds__(256) void cnt_k(const int* __restrict__ edst,
                                             int* __restrict__ cnt) {
    const int e = blockIdx.x * 256 + threadIdx.x;
    if (e < NE) atomicAdd(&cnt[edst[e]], 1);
}

// Block-level exclusive scan (256 elems/block); writes block total to partials.
__global__ __launch_bounds__(256) void scan1_k(const int* __restrict__ cnt,
                                               int* __restrict__ rp,
                                               int* __restrict__ partials) {
    __shared__ int s[256];
    const int t = threadIdx.x;
    const int i = blockIdx.x * 256 + t;
    const int v = (i < NN) ? cnt[i] : 0;
    s[t] = v;
    __syncthreads();
#pragma unroll
    for (int off = 1; off < 256; off <<= 1) {
        int a = (t >= off) ? s[t - off] : 0;
        __syncthreads();
        s[t] += a;
        __syncthreads();
    }
    if (i < NN) rp[i] = s[t] - v;             // exclusive, block-local
    if (t == 255) partials[blockIdx.x] = s[t]; // inclusive total
}

// Single-block exclusive scan of partials (NB1 <= 512).
__global__ __launch_bounds__(512) void scan2_k(int* __restrict__ partials, int nb) {
    __shared__ int s[512];
    const int t = threadIdx.x;
    const int v = (t < nb) ? partials[t] : 0;
    s[t] = v;
    __syncthreads();
#pragma unroll
    for (int off = 1; off < 512; off <<= 1) {
        int a = (t >= off) ? s[t - off] : 0;
        __syncthreads();
        s[t] += a;
        __syncthreads();
    }
    if (t < nb) partials[t] = s[t] - v;        // exclusive
}

__global__ __launch_bounds__(256) void scan3_k(int* __restrict__ rp,
                                               const int* __restrict__ partials) {
    const int i = blockIdx.x * 256 + threadIdx.x;
    if (i < NN) rp[i] += partials[blockIdx.x];
    else if (i == NN) rp[NN] = NE;
}

__global__ __launch_bounds__(256) void scat_k(const int* __restrict__ esrc,
                                              const int* __restrict__ edst,
                                              const float* __restrict__ ew,
                                              const int* __restrict__ rp,
                                              int* __restrict__ fill,
                                              int* __restrict__ srcs_s,
                                              float* __restrict__ ws_s) {
    const int e = blockIdx.x * 256 + threadIdx.x;
    if (e >= NE) return;
    const int d = edst[e];
    const int pos = rp[d] + atomicAdd(&fill[d], 1);
    srcs_s[pos] = esrc[e];
    ws_s[pos] = ew[e];
}

// ============================ SpMM gather =================================
// hacc[n][f] = sum_{j in [rp[n],rp[n+1])} ws_s[j] * xw[srcs_s[j]][f]
// 128 threads per node (f), 2 nodes per 256-block.
__global__ __launch_bounds__(256) void spmm1_g(const int* __restrict__ rp,
                                               const int* __restrict__ srcs_s,
                                               const float* __restrict__ ws_s,
                                               const float* __restrict__ xw,
                                               float* __restrict__ hacc) {
    const int n = blockIdx.x * 2 + (threadIdx.x >> 7);
    const int f = threadIdx.x & 127;
    const int beg = rp[n], end = rp[n + 1];
    float acc = 0.f;
    int j = beg;
    for (; j + 1 < end; j += 2) {
        const int s0 = srcs_s[j], s1 = srcs_s[j + 1];
        const float w0 = ws_s[j], w1 = ws_s[j + 1];
        const float v0 = xw[(size_t)s0 * NH + f];
        const float v1 = xw[(size_t)s1 * NH + f];
        acc = fmaf(w0, v0, acc);
        acc = fmaf(w1, v1, acc);
    }
    if (j < end) acc = fmaf(ws_s[j], xw[(size_t)srcs_s[j] * NH + f], acc);
    hacc[(size_t)n * NH + f] = acc;
}

// z[n][f] = sum ws_s[j] * hw[srcs_s[j]][f], f<40. 320 threads = 8 nodes/block.
__global__ __launch_bounds__(320) void spmm2_g(const int* __restrict__ rp,
                                               const int* __restrict__ srcs_s,
                                               const float* __restrict__ ws_s,
                                               const float* __restrict__ hw,
                                               float* __restrict__ z) {
    const int n = blockIdx.x * 8 + threadIdx.x / NC;
    const int f = threadIdx.x % NC;
    const int beg = rp[n], end = rp[n + 1];
    float acc = 0.f;
    int j = beg;
    for (; j + 1 < end; j += 2) {
        const int s0 = srcs_s[j], s1 = srcs_s[j + 1];
        const float w0 = ws_s[j], w1 = ws_s[j + 1];
        const float v0 = hw[(size_t)s0 * NC + f];
        const float v1 = hw[(size_t)s1 * NC + f];
        acc = fmaf(w0, v0, acc);
        acc = fmaf(w1, v1, acc);
    }
    if (j < end) acc = fmaf(ws_s[j], hw[(size_t)srcs_s[j] * NC + f], acc);
    z[(size_t)n * NC + f] = acc;
}

// ============================ atomic fallback =============================
__global__ __launch_bounds__(256) void spmm1_k(const int* __restrict__ esrc,
                                               const int* __restrict__ edst,
                                               const float* __restrict__ ew,
                                               const float* __restrict__ xw,
                                               float* __restrict__ hacc) {
    const unsigned int i = blockIdx.x * 256u + threadIdx.x;
    const unsigned int e = i >> 7;
    const unsigned int f = i & 127u;
    const int s = esrc[e];
    const int d = edst[e];
    atomicAdd(&hacc[(size_t)d * NH + f], ew[e] * xw[(size_t)s * NH + f]);
}

__global__ __launch_bounds__(256) void spmm2_k(const int* __restrict__ esrc,
                                               const int* __restrict__ edst,
                                               const float* __restrict__ ew,
                                               const float* __restrict__ hw,
                                               float* __restrict__ z) {
    const unsigned int i = blockIdx.x * 256u + threadIdx.x;
    if (i >= (unsigned int)NE * NC) return;
    const unsigned int e = i / NC;
    const unsigned int f = i - e * NC;
    const int s = esrc[e];
    const int d = edst[e];
    atomicAdd(&z[(size_t)d * NC + f], ew[e] * hw[(size_t)s * NC + f]);
}

// ============================ pointwise ===================================
__global__ __launch_bounds__(128) void norm_k(const float* __restrict__ hacc,
                                              const float* __restrict__ b0,
                                              float* __restrict__ h2) {
    const int n = blockIdx.x;
    const int f = threadIdx.x;
    const float v = hacc[(size_t)n * NH + f] + b0[f];
    float s = v * v;
#pragma unroll
    for (int o = 32; o > 0; o >>= 1) s += __shfl_down(s, o, 64);
    __shared__ float wsum[2];
    if ((threadIdx.x & 63) == 0) wsum[threadIdx.x >> 6] = s;
    __syncthreads();
    const float nrm = sqrtf(wsum[0] + wsum[1]);
    const float scale = 1.0f / fmaxf(nrm, 1e-12f);
    h2[(size_t)n * NH + f] = fmaxf(v * scale, 0.0f);
}

__global__ void gemm2_k(const float* __restrict__ h2,
                        const float* __restrict__ W1,
                        float* __restrict__ hw) {
    __shared__ float sW1[NH * NC];
    const int lt = threadIdx.y * NC + threadIdx.x;
    for (int i = lt; i < NH * NC; i += 240) sW1[i] = W1[i];
    __syncthreads();
    const int n = blockIdx.x * 6 + threadIdx.y;
    if (n >= NN) return;
    const int f = threadIdx.x;
    const float* hr = h2 + (size_t)n * NH;
    float acc = 0.f;
#pragma unroll 4
    for (int k = 0; k < NH; k += 4) {
        const float4 hv = *(const float4*)(hr + k);
        acc = fmaf(hv.x, sW1[(k + 0) * NC + f], acc);
        acc = fmaf(hv.y, sW1[(k + 1) * NC + f], acc);
        acc = fmaf(hv.z, sW1[(k + 2) * NC + f], acc);
        acc = fmaf(hv.w, sW1[(k + 3) * NC + f], acc);
    }
    hw[(size_t)n * NC + f] = acc;
}

__global__ __launch_bounds__(256) void lsm_k(float* __restrict__ z,
                                             const float* __restrict__ b1) {
    const int wave = threadIdx.x >> 6;
    const int lane = threadIdx.x & 63;
    const int n = blockIdx.x * 4 + wave;
    float v = -INFINITY;
    if (lane < NC) v = z[(size_t)n * NC + lane] + b1[lane];
    float m = v;
#pragma unroll
    for (int o = 32; o > 0; o >>= 1) m = fmaxf(m, __shfl_down(m, o, 64));
    m = __shfl(m, 0, 64);
    float ex = (lane < NC) ? expf(v - m) : 0.0f;
#pragma unroll
    for (int o = 32; o > 0; o >>= 1) ex += __shfl_down(ex, o, 64);
    const float lse = logf(__shfl(ex, 0, 64));
    if (lane < NC) z[(size_t)n * NC + lane] = v - m - lse;
}

// ============================ launch ======================================
extern "C" void kernel_launch(void* const* d_in, const int* in_sizes, int n_in,
                              void* d_out, int out_size, void* d_ws, size_t ws_size,
                              hipStream_t stream) {
    const float* x    = (const float*)d_in[0];
    const int*   esrc = (const int*)d_in[1];
    const int*   edst = (const int*)d_in[2];
    const float* ew   = (const float*)d_in[3];
    const float* W0   = (const float*)d_in[4];
    const float* b0   = (const float*)d_in[5];
    const float* W1   = (const float*)d_in[6];
    const float* b1   = (const float*)d_in[7];
    float* out = (float*)d_out;

    const int NB1 = (NN + 255) / 256;  // 391 scan blocks

    // workspace layout (4-byte words)
    size_t o = 0;
    float* bufA    = (float*)d_ws + o; o += (size_t)NN * NH;  // xw -> h2
    float* bufB    = (float*)d_ws + o; o += (size_t)NN * NH;  // hacc -> hw
    int*   srcs_s  = (int*)d_ws + o;   o += NE;
    float* ws_s    = (float*)d_ws + o; o += NE;
    int*   cnt     = (int*)d_ws + o;   o += NN;               // cnt+fill adjacent
    int*   fill    = (int*)d_ws + o;   o += NN;
    int*   rp      = (int*)d_ws + o;   o += NN + 2;
    int*   partials= (int*)d_ws + o;   o += 512;
    const bool csr_ok = (o * 4 <= ws_size);

    // 1. xw = x @ W0
    gemm1_k<<<NN / 4, 128, 0, stream>>>(x, W0, bufA);

    if (csr_ok) {
        // 2. CSR build: count -> scan -> scatter (rebuilt every call; ws re-poisoned)
        hipMemsetAsync(cnt, 0, 2 * (size_t)NN * sizeof(int), stream);  // cnt + fill
        cnt_k<<<(NE + 255) / 256, 256, 0, stream>>>(edst, cnt);
        scan1_k<<<NB1, 256, 0, stream>>>(cnt, rp, partials);
        scan2_k<<<1, 512, 0, stream>>>(partials, NB1);
        scan3_k<<<NB1, 256, 0, stream>>>(rp, partials);
        scat_k<<<(NE + 255) / 256, 256, 0, stream>>>(esrc, edst, ew, rp, fill, srcs_s, ws_s);
        // 3. hacc = gather-spmm(xw)
        spmm1_g<<<NN / 2, 256, 0, stream>>>(rp, srcs_s, ws_s, bufA, bufB);
        // 4. h2 = relu(l2norm(hacc + b0))
        norm_k<<<NN, 128, 0, stream>>>(bufB, b0, bufA);
        // 5. hw = h2 @ W1
        gemm2_k<<<(NN + 5) / 6, dim3(40, 6), 0, stream>>>(bufA, W1, bufB);
        // 6. z = gather-spmm(hw) directly into d_out
        spmm2_g<<<NN / 8, 320, 0, stream>>>(rp, srcs_s, ws_s, bufB, out);
    } else {
        hipMemsetAsync(bufB, 0, (size_t)NN * NH * sizeof(float), stream);
        spmm1_k<<<(NE * (size_t)NH) / 256, 256, 0, stream>>>(esrc, edst, ew, bufA, bufB);
        norm_k<<<NN, 128, 0, stream>>>(bufB, b0, bufA);
        gemm2_k<<<(NN + 5) / 6, dim3(40, 6), 0, stream>>>(bufA, W1, bufB);
        hipMemsetAsync(out, 0, (size_t)NN * NC * sizeof(float), stream);
        spmm2_k<<<((size_t)NE * NC + 255) / 256, 256, 0, stream>>>(esrc, edst, ew, bufB, out);
    }
    // 7. log_softmax(z + b1) in place
    lsm_k<<<NN / 4, 256, 0, stream>>>(out, b1);
}

// Round 3
// 1021.267 us; speedup vs baseline: 2.3446x; 1.2219x over previous
//
#include <hip/hip_runtime.h>
#include <math.h>

#define NN 100000
#define NE 3200000
#define NF 256
#define NH 128
#define NC 40

typedef unsigned int uint;

// ---- bf16 helpers (manual, RNE) ------------------------------------------
__device__ __forceinline__ float bflo(uint v) { return __uint_as_float(v << 16); }
__device__ __forceinline__ float bfhi(uint v) { return __uint_as_float(v & 0xffff0000u); }
__device__ __forceinline__ unsigned short f2bf(float f) {
    const uint u = __float_as_uint(f);
    return (unsigned short)((u + 0x7fffu + ((u >> 16) & 1u)) >> 16);  // round-nearest-even
}

// ============================ GEMM1 =======================================
// xw[n][f] = sum_k x[n][k] * W0[k][f]; fp32 math, bf16 output.
// 128 threads (f), 4 nodes/block.
__global__ __launch_bounds__(128) void gemm1_k(const float* __restrict__ x,
                                               const float* __restrict__ W0,
                                               unsigned short* __restrict__ xwh) {
    const int f = threadIdx.x;
    const int n0 = blockIdx.x * 4;
    const float* xr = x + (size_t)n0 * NF;
    float a0 = 0.f, a1 = 0.f, a2 = 0.f, a3 = 0.f;
#pragma unroll 4
    for (int k = 0; k < NF; k += 4) {
        const float4 v0 = *(const float4*)(xr + k);
        const float4 v1 = *(const float4*)(xr + NF + k);
        const float4 v2 = *(const float4*)(xr + 2 * NF + k);
        const float4 v3 = *(const float4*)(xr + 3 * NF + k);
        const float w0 = W0[(size_t)(k + 0) * NH + f];
        const float w1 = W0[(size_t)(k + 1) * NH + f];
        const float w2 = W0[(size_t)(k + 2) * NH + f];
        const float w3 = W0[(size_t)(k + 3) * NH + f];
        a0 = fmaf(v0.x, w0, a0); a0 = fmaf(v0.y, w1, a0);
        a0 = fmaf(v0.z, w2, a0); a0 = fmaf(v0.w, w3, a0);
        a1 = fmaf(v1.x, w0, a1); a1 = fmaf(v1.y, w1, a1);
        a1 = fmaf(v1.z, w2, a1); a1 = fmaf(v1.w, w3, a1);
        a2 = fmaf(v2.x, w0, a2); a2 = fmaf(v2.y, w1, a2);
        a2 = fmaf(v2.z, w2, a2); a2 = fmaf(v2.w, w3, a2);
        a3 = fmaf(v3.x, w0, a3); a3 = fmaf(v3.y, w1, a3);
        a3 = fmaf(v3.z, w2, a3); a3 = fmaf(v3.w, w3, a3);
    }
    xwh[(size_t)(n0 + 0) * NH + f] = f2bf(a0);
    xwh[(size_t)(n0 + 1) * NH + f] = f2bf(a1);
    xwh[(size_t)(n0 + 2) * NH + f] = f2bf(a2);
    xwh[(size_t)(n0 + 3) * NH + f] = f2bf(a3);
}

// ============================ CSR build ===================================
__global__ __launch_bounds__(256) void cnt_k(const int* __restrict__ edst,
                                             int* __restrict__ cnt) {
    const int e = blockIdx.x * 256 + threadIdx.x;
    if (e < NE) atomicAdd(&cnt[edst[e]], 1);
}

__global__ __launch_bounds__(256) void scan1_k(const int* __restrict__ cnt,
                                               int* __restrict__ rp,
                                               int* __restrict__ partials) {
    __shared__ int s[256];
    const int t = threadIdx.x;
    const int i = blockIdx.x * 256 + t;
    const int v = (i < NN) ? cnt[i] : 0;
    s[t] = v;
    __syncthreads();
#pragma unroll
    for (int off = 1; off < 256; off <<= 1) {
        int a = (t >= off) ? s[t - off] : 0;
        __syncthreads();
        s[t] += a;
        __syncthreads();
    }
    if (i < NN) rp[i] = s[t] - v;
    if (t == 255) partials[blockIdx.x] = s[t];
}

__global__ __launch_bounds__(512) void scan2_k(int* __restrict__ partials, int nb) {
    __shared__ int s[512];
    const int t = threadIdx.x;
    const int v = (t < nb) ? partials[t] : 0;
    s[t] = v;
    __syncthreads();
#pragma unroll
    for (int off = 1; off < 512; off <<= 1) {
        int a = (t >= off) ? s[t - off] : 0;
        __syncthreads();
        s[t] += a;
        __syncthreads();
    }
    if (t < nb) partials[t] = s[t] - v;
}

// adds block offsets; also seeds fill[] with the absolute row start.
__global__ __launch_bounds__(256) void scan3_k(int* __restrict__ rp,
                                               int* __restrict__ fill,
                                               const int* __restrict__ partials) {
    const int i = blockIdx.x * 256 + threadIdx.x;
    if (i < NN) {
        const int v = rp[i] + partials[blockIdx.x];
        rp[i] = v;
        fill[i] = v;
    } else if (i == NN) {
        rp[NN] = NE;
    }
}

// scatter packed (src, w_bits) with a single 8 B store.
__global__ __launch_bounds__(256) void scat_k(const int* __restrict__ esrc,
                                              const int* __restrict__ edst,
                                              const float* __restrict__ ew,
                                              int* __restrict__ fill,
                                              uint2* __restrict__ ep) {
    const int e = blockIdx.x * 256 + threadIdx.x;
    if (e >= NE) return;
    const int pos = atomicAdd(&fill[edst[e]], 1);
    ep[pos] = make_uint2((uint)esrc[e], __float_as_uint(ew[e]));
}

// ============================ SpMM1 gather (bf16) =========================
// 64 lanes per node (one wave), lane t handles feats {2t, 2t+1}.
// 4 nodes per 256-block; 4-edge unroll for 4 gathers in flight.
__global__ __launch_bounds__(256) void spmm1_g(const int* __restrict__ rp,
                                               const uint2* __restrict__ ep,
                                               const uint* __restrict__ xwb,
                                               float2* __restrict__ hacc2) {
    const int n = blockIdx.x * 4 + (threadIdx.x >> 6);
    const int t = threadIdx.x & 63;
    const int beg = rp[n], end = rp[n + 1];
    float a0 = 0.f, a1 = 0.f;
    int j = beg;
    for (; j + 3 < end; j += 4) {
        const uint2 e0 = ep[j], e1 = ep[j + 1], e2 = ep[j + 2], e3 = ep[j + 3];
        const uint v0 = xwb[(size_t)e0.x * 64 + t];
        const uint v1 = xwb[(size_t)e1.x * 64 + t];
        const uint v2 = xwb[(size_t)e2.x * 64 + t];
        const uint v3 = xwb[(size_t)e3.x * 64 + t];
        const float w0 = __uint_as_float(e0.y), w1 = __uint_as_float(e1.y);
        const float w2 = __uint_as_float(e2.y), w3 = __uint_as_float(e3.y);
        a0 = fmaf(w0, bflo(v0), a0); a1 = fmaf(w0, bfhi(v0), a1);
        a0 = fmaf(w1, bflo(v1), a0); a1 = fmaf(w1, bfhi(v1), a1);
        a0 = fmaf(w2, bflo(v2), a0); a1 = fmaf(w2, bfhi(v2), a1);
        a0 = fmaf(w3, bflo(v3), a0); a1 = fmaf(w3, bfhi(v3), a1);
    }
    for (; j < end; ++j) {
        const uint2 e = ep[j];
        const uint v = xwb[(size_t)e.x * 64 + t];
        const float w = __uint_as_float(e.y);
        a0 = fmaf(w, bflo(v), a0); a1 = fmaf(w, bfhi(v), a1);
    }
    hacc2[(size_t)n * 64 + t] = make_float2(a0, a1);
}

// ============================ SpMM2 gather (bf16) =========================
// 20 lanes per node (feats packed 2/lane), 16 nodes per 320-block.
__global__ __launch_bounds__(320) void spmm2_g(const int* __restrict__ rp,
                                               const uint2* __restrict__ ep,
                                               const uint* __restrict__ hwb,
                                               float2* __restrict__ z2) {
    const int n = blockIdx.x * 16 + threadIdx.x / 20;
    const int t = threadIdx.x % 20;
    const int beg = rp[n], end = rp[n + 1];
    float a0 = 0.f, a1 = 0.f;
    int j = beg;
    for (; j + 3 < end; j += 4) {
        const uint2 e0 = ep[j], e1 = ep[j + 1], e2 = ep[j + 2], e3 = ep[j + 3];
        const uint v0 = hwb[(size_t)e0.x * 20 + t];
        const uint v1 = hwb[(size_t)e1.x * 20 + t];
        const uint v2 = hwb[(size_t)e2.x * 20 + t];
        const uint v3 = hwb[(size_t)e3.x * 20 + t];
        const float w0 = __uint_as_float(e0.y), w1 = __uint_as_float(e1.y);
        const float w2 = __uint_as_float(e2.y), w3 = __uint_as_float(e3.y);
        a0 = fmaf(w0, bflo(v0), a0); a1 = fmaf(w0, bfhi(v0), a1);
        a0 = fmaf(w1, bflo(v1), a0); a1 = fmaf(w1, bfhi(v1), a1);
        a0 = fmaf(w2, bflo(v2), a0); a1 = fmaf(w2, bfhi(v2), a1);
        a0 = fmaf(w3, bflo(v3), a0); a1 = fmaf(w3, bfhi(v3), a1);
    }
    for (; j < end; ++j) {
        const uint2 e = ep[j];
        const uint v = hwb[(size_t)e.x * 20 + t];
        const float w = __uint_as_float(e.y);
        a0 = fmaf(w, bflo(v), a0); a1 = fmaf(w, bfhi(v), a1);
    }
    z2[(size_t)n * 20 + t] = make_float2(a0, a1);
}

// ============================ pointwise ===================================
// bias + L2 normalize + ReLU, in place (block == row, reads precede writes).
__global__ __launch_bounds__(128) void norm_k(float* __restrict__ h,
                                              const float* __restrict__ b0) {
    const int n = blockIdx.x;
    const int f = threadIdx.x;
    const float v = h[(size_t)n * NH + f] + b0[f];
    float s = v * v;
#pragma unroll
    for (int o = 32; o > 0; o >>= 1) s += __shfl_down(s, o, 64);
    __shared__ float wsum[2];
    if ((threadIdx.x & 63) == 0) wsum[threadIdx.x >> 6] = s;
    __syncthreads();
    const float nrm = sqrtf(wsum[0] + wsum[1]);
    const float scale = 1.0f / fmaxf(nrm, 1e-12f);
    h[(size_t)n * NH + f] = fmaxf(v * scale, 0.0f);
}

// GEMM2: hw[n][f] = sum_k h2[n][k] * W1[k][f]; fp32 math, bf16 out.
__global__ void gemm2_k(const float* __restrict__ h2,
                        const float* __restrict__ W1,
                        unsigned short* __restrict__ hwh) {
    __shared__ float sW1[NH * NC];
    const int lt = threadIdx.y * NC + threadIdx.x;
    for (int i = lt; i < NH * NC; i += 240) sW1[i] = W1[i];
    __syncthreads();
    const int n = blockIdx.x * 6 + threadIdx.y;
    if (n >= NN) return;
    const int f = threadIdx.x;
    const float* hr = h2 + (size_t)n * NH;
    float acc = 0.f;
#pragma unroll 4
    for (int k = 0; k < NH; k += 4) {
        const float4 hv = *(const float4*)(hr + k);
        acc = fmaf(hv.x, sW1[(k + 0) * NC + f], acc);
        acc = fmaf(hv.y, sW1[(k + 1) * NC + f], acc);
        acc = fmaf(hv.z, sW1[(k + 2) * NC + f], acc);
        acc = fmaf(hv.w, sW1[(k + 3) * NC + f], acc);
    }
    hwh[(size_t)n * NC + f] = f2bf(acc);
}

__global__ __launch_bounds__(256) void lsm_k(float* __restrict__ z,
                                             const float* __restrict__ b1) {
    const int wave = threadIdx.x >> 6;
    const int lane = threadIdx.x & 63;
    const int n = blockIdx.x * 4 + wave;
    float v = -INFINITY;
    if (lane < NC) v = z[(size_t)n * NC + lane] + b1[lane];
    float m = v;
#pragma unroll
    for (int o = 32; o > 0; o >>= 1) m = fmaxf(m, __shfl_down(m, o, 64));
    m = __shfl(m, 0, 64);
    float ex = (lane < NC) ? expf(v - m) : 0.0f;
#pragma unroll
    for (int o = 32; o > 0; o >>= 1) ex += __shfl_down(ex, o, 64);
    const float lse = logf(__shfl(ex, 0, 64));
    if (lane < NC) z[(size_t)n * NC + lane] = v - m - lse;
}

// ============================ launch ======================================
extern "C" void kernel_launch(void* const* d_in, const int* in_sizes, int n_in,
                              void* d_out, int out_size, void* d_ws, size_t ws_size,
                              hipStream_t stream) {
    const float* x    = (const float*)d_in[0];
    const int*   esrc = (const int*)d_in[1];
    const int*   edst = (const int*)d_in[2];
    const float* ew   = (const float*)d_in[3];
    const float* W0   = (const float*)d_in[4];
    const float* b0   = (const float*)d_in[5];
    const float* W1   = (const float*)d_in[6];
    const float* b1   = (const float*)d_in[7];
    float* out = (float*)d_out;

    const int NB1 = (NN + 255) / 256;  // 391

    // workspace layout (4-byte words); ep needs 8 B alignment (offset even).
    size_t o = 0;
    uint*  xwb  = (uint*)d_ws + o;  o += (size_t)NN * 64;       // xw bf16x2   25.6 MB
    float* hacc = (float*)d_ws + o; o += (size_t)NN * NH;       // hacc/h2     51.2 MB
    uint*  hwb  = (uint*)d_ws + o;  o += (size_t)NN * 20;       // hw bf16x2    8.0 MB
    uint2* ep   = (uint2*)((uint*)d_ws + o); o += (size_t)NE * 2; // edges     25.6 MB
    int*   cnt  = (int*)d_ws + o;   o += NN;
    int*   fill = (int*)d_ws + o;   o += NN;
    int*   rp   = (int*)d_ws + o;   o += NN + 2;
    int*   partials = (int*)d_ws + o; o += 512;

    // 1. xw = bf16(x @ W0)
    gemm1_k<<<NN / 4, 128, 0, stream>>>(x, W0, (unsigned short*)xwb);

    // 2. CSR build (rebuilt every call; ws is re-poisoned by harness)
    hipMemsetAsync(cnt, 0, (size_t)NN * sizeof(int), stream);
    cnt_k<<<(NE + 255) / 256, 256, 0, stream>>>(edst, cnt);
    scan1_k<<<NB1, 256, 0, stream>>>(cnt, rp, partials);
    scan2_k<<<1, 512, 0, stream>>>(partials, NB1);
    scan3_k<<<NB1, 256, 0, stream>>>(rp, fill, partials);
    scat_k<<<(NE + 255) / 256, 256, 0, stream>>>(esrc, edst, ew, fill, ep);

    // 3. hacc = gather-spmm(xw)
    spmm1_g<<<NN / 4, 256, 0, stream>>>(rp, ep, xwb, (float2*)hacc);
    // 4. h2 = relu(l2norm(hacc + b0)) in place
    norm_k<<<NN, 128, 0, stream>>>(hacc, b0);
    // 5. hw = bf16(h2 @ W1)
    gemm2_k<<<(NN + 5) / 6, dim3(40, 6), 0, stream>>>(hacc, W1, (unsigned short*)hwb);
    // 6. z = gather-spmm(hw) into d_out
    spmm2_g<<<NN / 16, 320, 0, stream>>>(rp, ep, hwb, (float2*)out);
    // 7. log_softmax(z + b1) in place
    lsm_k<<<NN / 4, 256, 0, stream>>>(out, b1);
}

// Round 4
// 766.381 us; speedup vs baseline: 3.1243x; 1.3326x over previous
//
#include <hip/hip_runtime.h>
#include <math.h>

#define NN 100000
#define NE 3200000
#define NF 256
#define NH 128
#define NC 40

#define CH 8192                    // edges per pass-1 block
#define NBLK 391                   // ceil(NE/CH)
#define NBUCK 782                  // ceil(NN/128) buckets of 128 dsts
#define HTOT (NBUCK * NBLK)        // 305762
#define HS1 ((HTOT + 511) / 512)   // 598 scan blocks

typedef unsigned int uint;

// ---- bf16 helpers (manual, RNE) ------------------------------------------
__device__ __forceinline__ float bflo(uint v) { return __uint_as_float(v << 16); }
__device__ __forceinline__ float bfhi(uint v) { return __uint_as_float(v & 0xffff0000u); }
__device__ __forceinline__ unsigned short f2bf(float f) {
    const uint u = __float_as_uint(f);
    return (unsigned short)((u + 0x7fffu + ((u >> 16) & 1u)) >> 16);
}

// ============================ GEMM1 =======================================
__global__ __launch_bounds__(128) void gemm1_k(const float* __restrict__ x,
                                               const float* __restrict__ W0,
                                               unsigned short* __restrict__ xwh) {
    const int f = threadIdx.x;
    const int n0 = blockIdx.x * 4;
    const float* xr = x + (size_t)n0 * NF;
    float a0 = 0.f, a1 = 0.f, a2 = 0.f, a3 = 0.f;
#pragma unroll 4
    for (int k = 0; k < NF; k += 4) {
        const float4 v0 = *(const float4*)(xr + k);
        const float4 v1 = *(const float4*)(xr + NF + k);
        const float4 v2 = *(const float4*)(xr + 2 * NF + k);
        const float4 v3 = *(const float4*)(xr + 3 * NF + k);
        const float w0 = W0[(size_t)(k + 0) * NH + f];
        const float w1 = W0[(size_t)(k + 1) * NH + f];
        const float w2 = W0[(size_t)(k + 2) * NH + f];
        const float w3 = W0[(size_t)(k + 3) * NH + f];
        a0 = fmaf(v0.x, w0, a0); a0 = fmaf(v0.y, w1, a0);
        a0 = fmaf(v0.z, w2, a0); a0 = fmaf(v0.w, w3, a0);
        a1 = fmaf(v1.x, w0, a1); a1 = fmaf(v1.y, w1, a1);
        a1 = fmaf(v1.z, w2, a1); a1 = fmaf(v1.w, w3, a1);
        a2 = fmaf(v2.x, w0, a2); a2 = fmaf(v2.y, w1, a2);
        a2 = fmaf(v2.z, w2, a2); a2 = fmaf(v2.w, w3, a2);
        a3 = fmaf(v3.x, w0, a3); a3 = fmaf(v3.y, w1, a3);
        a3 = fmaf(v3.z, w2, a3); a3 = fmaf(v3.w, w3, a3);
    }
    xwh[(size_t)(n0 + 0) * NH + f] = f2bf(a0);
    xwh[(size_t)(n0 + 1) * NH + f] = f2bf(a1);
    xwh[(size_t)(n0 + 2) * NH + f] = f2bf(a2);
    xwh[(size_t)(n0 + 3) * NH + f] = f2bf(a3);
}

// ======================= CSR build: pass 1 histogram ======================
__global__ __launch_bounds__(256) void p1hist_k(const int* __restrict__ edst,
                                                int* __restrict__ hmat) {
    __shared__ uint h[NBUCK];
    for (int i = threadIdx.x; i < NBUCK; i += 256) h[i] = 0;
    __syncthreads();
    const int b = blockIdx.x;
    const int e0 = b * CH, e1 = min(NE, e0 + CH);
    for (int e = e0 + threadIdx.x; e < e1; e += 256)
        atomicAdd(&h[((uint)edst[e]) >> 7], 1u);
    __syncthreads();
    for (int i = threadIdx.x; i < NBUCK; i += 256)
        hmat[(size_t)i * NBLK + b] = (int)h[i];
}

// ======================= scan of hmat (306K ints) =========================
__global__ __launch_bounds__(512) void hscan1_k(int* __restrict__ hmat,
                                                int* __restrict__ partials) {
    __shared__ int s[512];
    const int t = threadIdx.x;
    const int i = blockIdx.x * 512 + t;
    const int v = (i < HTOT) ? hmat[i] : 0;
    s[t] = v;
    __syncthreads();
#pragma unroll
    for (int off = 1; off < 512; off <<= 1) {
        int a = (t >= off) ? s[t - off] : 0;
        __syncthreads();
        s[t] += a;
        __syncthreads();
    }
    if (i < HTOT) hmat[i] = s[t] - v;          // exclusive, block-local
    if (t == 511) partials[blockIdx.x] = s[t];
}

__global__ __launch_bounds__(1024) void hscan2_k(int* __restrict__ partials, int nb) {
    __shared__ int s[1024];
    const int t = threadIdx.x;
    const int v = (t < nb) ? partials[t] : 0;
    s[t] = v;
    __syncthreads();
#pragma unroll
    for (int off = 1; off < 1024; off <<= 1) {
        int a = (t >= off) ? s[t - off] : 0;
        __syncthreads();
        s[t] += a;
        __syncthreads();
    }
    if (t < nb) partials[t] = s[t] - v;        // exclusive
}

__global__ __launch_bounds__(512) void hscan3_k(int* __restrict__ hmat,
                                                const int* __restrict__ partials) {
    const int i = blockIdx.x * 512 + threadIdx.x;
    if (i < HTOT) hmat[i] += partials[blockIdx.x];
}

// ======================= pass 1 scatter (block-private ranges) ============
// payload: x = src | (dst&127)<<17 ; y = w bits
__global__ __launch_bounds__(256) void p1scat_k(const int* __restrict__ esrc,
                                                const int* __restrict__ edst,
                                                const float* __restrict__ ew,
                                                const int* __restrict__ hmat,
                                                uint2* __restrict__ ep1) {
    __shared__ uint base[NBUCK];
    const int b = blockIdx.x;
    for (int i = threadIdx.x; i < NBUCK; i += 256)
        base[i] = (uint)hmat[(size_t)i * NBLK + b];
    __syncthreads();
    const int e0 = b * CH, e1 = min(NE, e0 + CH);
    for (int e = e0 + threadIdx.x; e < e1; e += 256) {
        const uint d = (uint)edst[e];
        const uint pos = atomicAdd(&base[d >> 7], 1u);
        ep1[pos] = make_uint2((uint)esrc[e] | ((d & 127u) << 17), __float_as_uint(ew[e]));
    }
}

// ======================= pass 2: in-bucket sort -> CSR + rp ===============
__global__ __launch_bounds__(256) void p2_k(const int* __restrict__ hmat,
                                            const uint2* __restrict__ ep1,
                                            uint2* __restrict__ ep,
                                            int* __restrict__ rp) {
    const int bk = blockIdx.x;
    const int beg = hmat[(size_t)bk * NBLK];
    const int end = (bk == NBUCK - 1) ? NE : hmat[(size_t)(bk + 1) * NBLK];
    __shared__ uint cnt[128];
    __shared__ uint st[128];
    if (threadIdx.x < 128) cnt[threadIdx.x] = 0;
    __syncthreads();
    for (int j = beg + threadIdx.x; j < end; j += 256)
        atomicAdd(&cnt[(ep1[j].x >> 17) & 127u], 1u);
    __syncthreads();
    if (threadIdx.x < 128) st[threadIdx.x] = cnt[threadIdx.x];
    __syncthreads();
#pragma unroll
    for (int off = 1; off < 128; off <<= 1) {
        uint a = 0;
        if (threadIdx.x < 128 && threadIdx.x >= off) a = st[threadIdx.x - off];
        __syncthreads();
        if (threadIdx.x < 128) st[threadIdx.x] += a;
        __syncthreads();
    }
    if (threadIdx.x < 128) {
        const uint start = st[threadIdx.x] - cnt[threadIdx.x];  // exclusive
        const int d = bk * 128 + threadIdx.x;
        if (d < NN) rp[d] = beg + (int)start;
        cnt[threadIdx.x] = (uint)beg + start;  // running absolute fill position
    }
    if (bk == 0 && threadIdx.x == 200) rp[NN] = NE;
    __syncthreads();
    for (int j = beg + threadIdx.x; j < end; j += 256) {
        const uint2 r = ep1[j];
        const uint pos = atomicAdd(&cnt[(r.x >> 17) & 127u], 1u);
        ep[pos] = r;  // block-private 33 KB region: lines assemble in this CU's L2
    }
}

// ============================ SpMM1 gather (bf16) =========================
__global__ __launch_bounds__(256) void spmm1_g(const int* __restrict__ rp,
                                               const uint2* __restrict__ ep,
                                               const uint* __restrict__ xwb,
                                               float2* __restrict__ hacc2) {
    const int n = blockIdx.x * 4 + (threadIdx.x >> 6);
    const int t = threadIdx.x & 63;
    const int beg = rp[n], end = rp[n + 1];
    float a0 = 0.f, a1 = 0.f;
    int j = beg;
    for (; j + 3 < end; j += 4) {
        const uint2 e0 = ep[j], e1 = ep[j + 1], e2 = ep[j + 2], e3 = ep[j + 3];
        const uint v0 = xwb[(size_t)(e0.x & 0x1FFFFu) * 64 + t];
        const uint v1 = xwb[(size_t)(e1.x & 0x1FFFFu) * 64 + t];
        const uint v2 = xwb[(size_t)(e2.x & 0x1FFFFu) * 64 + t];
        const uint v3 = xwb[(size_t)(e3.x & 0x1FFFFu) * 64 + t];
        const float w0 = __uint_as_float(e0.y), w1 = __uint_as_float(e1.y);
        const float w2 = __uint_as_float(e2.y), w3 = __uint_as_float(e3.y);
        a0 = fmaf(w0, bflo(v0), a0); a1 = fmaf(w0, bfhi(v0), a1);
        a0 = fmaf(w1, bflo(v1), a0); a1 = fmaf(w1, bfhi(v1), a1);
        a0 = fmaf(w2, bflo(v2), a0); a1 = fmaf(w2, bfhi(v2), a1);
        a0 = fmaf(w3, bflo(v3), a0); a1 = fmaf(w3, bfhi(v3), a1);
    }
    for (; j < end; ++j) {
        const uint2 e = ep[j];
        const uint v = xwb[(size_t)(e.x & 0x1FFFFu) * 64 + t];
        const float w = __uint_as_float(e.y);
        a0 = fmaf(w, bflo(v), a0); a1 = fmaf(w, bfhi(v), a1);
    }
    hacc2[(size_t)n * 64 + t] = make_float2(a0, a1);
}

// ============================ SpMM2 gather (bf16) =========================
__global__ __launch_bounds__(320) void spmm2_g(const int* __restrict__ rp,
                                               const uint2* __restrict__ ep,
                                               const uint* __restrict__ hwb,
                                               float2* __restrict__ z2) {
    const int n = blockIdx.x * 16 + threadIdx.x / 20;
    const int t = threadIdx.x % 20;
    const int beg = rp[n], end = rp[n + 1];
    float a0 = 0.f, a1 = 0.f;
    int j = beg;
    for (; j + 3 < end; j += 4) {
        const uint2 e0 = ep[j], e1 = ep[j + 1], e2 = ep[j + 2], e3 = ep[j + 3];
        const uint v0 = hwb[(size_t)(e0.x & 0x1FFFFu) * 20 + t];
        const uint v1 = hwb[(size_t)(e1.x & 0x1FFFFu) * 20 + t];
        const uint v2 = hwb[(size_t)(e2.x & 0x1FFFFu) * 20 + t];
        const uint v3 = hwb[(size_t)(e3.x & 0x1FFFFu) * 20 + t];
        const float w0 = __uint_as_float(e0.y), w1 = __uint_as_float(e1.y);
        const float w2 = __uint_as_float(e2.y), w3 = __uint_as_float(e3.y);
        a0 = fmaf(w0, bflo(v0), a0); a1 = fmaf(w0, bfhi(v0), a1);
        a0 = fmaf(w1, bflo(v1), a0); a1 = fmaf(w1, bfhi(v1), a1);
        a0 = fmaf(w2, bflo(v2), a0); a1 = fmaf(w2, bfhi(v2), a1);
        a0 = fmaf(w3, bflo(v3), a0); a1 = fmaf(w3, bfhi(v3), a1);
    }
    for (; j < end; ++j) {
        const uint2 e = ep[j];
        const uint v = hwb[(size_t)(e.x & 0x1FFFFu) * 20 + t];
        const float w = __uint_as_float(e.y);
        a0 = fmaf(w, bflo(v), a0); a1 = fmaf(w, bfhi(v), a1);
    }
    z2[(size_t)n * 20 + t] = make_float2(a0, a1);
}

// ============================ pointwise ===================================
__global__ __launch_bounds__(128) void norm_k(float* __restrict__ h,
                                              const float* __restrict__ b0) {
    const int n = blockIdx.x;
    const int f = threadIdx.x;
    const float v = h[(size_t)n * NH + f] + b0[f];
    float s = v * v;
#pragma unroll
    for (int o = 32; o > 0; o >>= 1) s += __shfl_down(s, o, 64);
    __shared__ float wsum[2];
    if ((threadIdx.x & 63) == 0) wsum[threadIdx.x >> 6] = s;
    __syncthreads();
    const float nrm = sqrtf(wsum[0] + wsum[1]);
    const float scale = 1.0f / fmaxf(nrm, 1e-12f);
    h[(size_t)n * NH + f] = fmaxf(v * scale, 0.0f);
}

__global__ void gemm2_k(const float* __restrict__ h2,
                        const float* __restrict__ W1,
                        unsigned short* __restrict__ hwh) {
    __shared__ float sW1[NH * NC];
    const int lt = threadIdx.y * NC + threadIdx.x;
    for (int i = lt; i < NH * NC; i += 240) sW1[i] = W1[i];
    __syncthreads();
    const int n = blockIdx.x * 6 + threadIdx.y;
    if (n >= NN) return;
    const int f = threadIdx.x;
    const float* hr = h2 + (size_t)n * NH;
    float acc = 0.f;
#pragma unroll 4
    for (int k = 0; k < NH; k += 4) {
        const float4 hv = *(const float4*)(hr + k);
        acc = fmaf(hv.x, sW1[(k + 0) * NC + f], acc);
        acc = fmaf(hv.y, sW1[(k + 1) * NC + f], acc);
        acc = fmaf(hv.z, sW1[(k + 2) * NC + f], acc);
        acc = fmaf(hv.w, sW1[(k + 3) * NC + f], acc);
    }
    hwh[(size_t)n * NC + f] = f2bf(acc);
}

__global__ __launch_bounds__(256) void lsm_k(float* __restrict__ z,
                                             const float* __restrict__ b1) {
    const int wave = threadIdx.x >> 6;
    const int lane = threadIdx.x & 63;
    const int n = blockIdx.x * 4 + wave;
    float v = -INFINITY;
    if (lane < NC) v = z[(size_t)n * NC + lane] + b1[lane];
    float m = v;
#pragma unroll
    for (int o = 32; o > 0; o >>= 1) m = fmaxf(m, __shfl_down(m, o, 64));
    m = __shfl(m, 0, 64);
    float ex = (lane < NC) ? expf(v - m) : 0.0f;
#pragma unroll
    for (int o = 32; o > 0; o >>= 1) ex += __shfl_down(ex, o, 64);
    const float lse = logf(__shfl(ex, 0, 64));
    if (lane < NC) z[(size_t)n * NC + lane] = v - m - lse;
}

// ============================ launch ======================================
extern "C" void kernel_launch(void* const* d_in, const int* in_sizes, int n_in,
                              void* d_out, int out_size, void* d_ws, size_t ws_size,
                              hipStream_t stream) {
    const float* x    = (const float*)d_in[0];
    const int*   esrc = (const int*)d_in[1];
    const int*   edst = (const int*)d_in[2];
    const float* ew   = (const float*)d_in[3];
    const float* W0   = (const float*)d_in[4];
    const float* b0   = (const float*)d_in[5];
    const float* W1   = (const float*)d_in[6];
    const float* b1   = (const float*)d_in[7];
    float* out = (float*)d_out;

    // workspace layout (4-byte words); all uint2 arrays at even word offsets.
    size_t o = 0;
    uint*  xwb  = (uint*)d_ws + o;  o += (size_t)NN * 64;        // 25.6 MB
    float* hacc = (float*)d_ws + o; o += (size_t)NN * NH;        // 51.2 MB (ep1 aliases)
    uint2* ep1  = (uint2*)hacc;                                  // dead once p2 finishes
    uint*  hwb  = (uint*)d_ws + o;  o += (size_t)NN * 20;        //  8.0 MB
    uint2* ep   = (uint2*)((uint*)d_ws + o); o += (size_t)NE * 2; // 25.6 MB
    int*   hmat = (int*)d_ws + o;   o += HTOT;                   //  1.2 MB
    int*   rp   = (int*)d_ws + o;   o += NN + 2;
    int*   partials = (int*)d_ws + o; o += 1024;

    // 1. xw = bf16(x @ W0)
    gemm1_k<<<NN / 4, 128, 0, stream>>>(x, W0, (unsigned short*)xwb);

    // 2. CSR build: two-pass counting sort, block-private write ranges
    p1hist_k<<<NBLK, 256, 0, stream>>>(edst, hmat);
    hscan1_k<<<HS1, 512, 0, stream>>>(hmat, partials);
    hscan2_k<<<1, 1024, 0, stream>>>(partials, HS1);
    hscan3_k<<<HS1, 512, 0, stream>>>(hmat, partials);
    p1scat_k<<<NBLK, 256, 0, stream>>>(esrc, edst, ew, hmat, ep1);
    p2_k<<<NBUCK, 256, 0, stream>>>(hmat, ep1, ep, rp);

    // 3. hacc = gather-spmm(xw)   (overwrites ep1 region — ep1 is dead now)
    spmm1_g<<<NN / 4, 256, 0, stream>>>(rp, ep, xwb, (float2*)hacc);
    // 4. h2 = relu(l2norm(hacc + b0)) in place
    norm_k<<<NN, 128, 0, stream>>>(hacc, b0);
    // 5. hw = bf16(h2 @ W1)
    gemm2_k<<<(NN + 5) / 6, dim3(40, 6), 0, stream>>>(hacc, W1, (unsigned short*)hwb);
    // 6. z = gather-spmm(hw) into d_out
    spmm2_g<<<NN / 16, 320, 0, stream>>>(rp, ep, hwb, (float2*)out);
    // 7. log_softmax(z + b1) in place
    lsm_k<<<NN / 4, 256, 0, stream>>>(out, b1);
}

// Round 5
// 645.120 us; speedup vs baseline: 3.7116x; 1.1880x over previous
//
#include <hip/hip_runtime.h>
#include <math.h>

#define NN 100000
#define NE 3200000
#define NF 256
#define NH 128
#define NC 40

#define CH 8192                    // edges per pass-1 block
#define NBLK 391                   // ceil(NE/CH)
#define NBUCK 782                  // ceil(NN/128) buckets of 128 dsts
#define HTOT (NBUCK * NBLK)        // 305762
#define HS1 ((HTOT + 511) / 512)   // 598 scan blocks

typedef unsigned int uint;
typedef short short8 __attribute__((ext_vector_type(8)));
typedef float floatx4 __attribute__((ext_vector_type(4)));

// ---- bf16 helpers (manual, RNE) ------------------------------------------
__device__ __forceinline__ float bflo(uint v) { return __uint_as_float(v << 16); }
__device__ __forceinline__ float bfhi(uint v) { return __uint_as_float(v & 0xffff0000u); }
__device__ __forceinline__ unsigned short f2bf(float f) {
    const uint u = __float_as_uint(f);
    return (unsigned short)((u + 0x7fffu + ((u >> 16) & 1u)) >> 16);
}
__device__ __forceinline__ uint pack2bf(float a, float b) {
    return (uint)f2bf(a) | ((uint)f2bf(b) << 16);
}

union ABfrag { uint u[4]; short8 s; };

// ================= W0 pre-pack into MFMA B-fragment order =================
// entry e = (kstep*8 + ntile)*64 + lane; 4 words of bf16x2 (j = 0..7)
// B[k][n]: n = ntile*16 + (lane&15), k = kstep*32 + (lane>>4)*8 + j
__global__ __launch_bounds__(256) void w0pack_k(const float* __restrict__ W0,
                                                uint4* __restrict__ W0p) {
    const int idx = blockIdx.x * 256 + threadIdx.x;  // 4096 entries
    if (idx >= 4096) return;
    const int lane  = idx & 63;
    const int ntile = (idx >> 6) & 7;
    const int kstep = idx >> 9;
    const int n  = ntile * 16 + (lane & 15);
    const int kb = kstep * 32 + (lane >> 4) * 8;
    uint w[4];
#pragma unroll
    for (int ww = 0; ww < 4; ++ww)
        w[ww] = pack2bf(W0[(size_t)(kb + 2 * ww) * NH + n],
                        W0[(size_t)(kb + 2 * ww + 1) * NH + n]);
    W0p[idx] = make_uint4(w[0], w[1], w[2], w[3]);
}

// ============================ GEMM1 (MFMA bf16) ===========================
// block = 256 (4 waves), each wave: 16 rows x 128 cols, K=256 in 8 steps.
// A from global x (fp32 -> bf16 in-register); B staged in LDS (64 KB).
__global__ __launch_bounds__(256) void gemm1_mfma(const float* __restrict__ x,
                                                  const uint4* __restrict__ W0p,
                                                  unsigned short* __restrict__ xwh) {
    __shared__ __align__(16) uint4 sB[4096];  // 64 KB: [kstep][ntile][lane]
    for (int i = threadIdx.x; i < 4096; i += 256) sB[i] = W0p[i];
    __syncthreads();

    const int wave = threadIdx.x >> 6;
    const int lane = threadIdx.x & 63;
    const int quad = lane >> 4;
    const int mcol = lane & 15;                    // C/D col, A row-within-tile
    const int row  = blockIdx.x * 64 + wave * 16 + mcol;
    const int rowc = min(row, NN - 1);
    const float* xr = x + (size_t)rowc * NF + quad * 8;

    floatx4 acc[8] = {};
    float4 lo = *(const float4*)(xr);
    float4 hi = *(const float4*)(xr + 4);
#pragma unroll
    for (int ks = 0; ks < 8; ++ks) {
        ABfrag a;
        a.u[0] = pack2bf(lo.x, lo.y);
        a.u[1] = pack2bf(lo.z, lo.w);
        a.u[2] = pack2bf(hi.x, hi.y);
        a.u[3] = pack2bf(hi.z, hi.w);
        if (ks < 7) {  // prefetch next k-chunk while MFMAs run
            lo = *(const float4*)(xr + (ks + 1) * 32);
            hi = *(const float4*)(xr + (ks + 1) * 32 + 4);
        }
#pragma unroll
        for (int nt = 0; nt < 8; ++nt) {
            ABfrag b;
            const uint4 bw = sB[(ks * 8 + nt) * 64 + lane];
            b.u[0] = bw.x; b.u[1] = bw.y; b.u[2] = bw.z; b.u[3] = bw.w;
            acc[nt] = __builtin_amdgcn_mfma_f32_16x16x32_bf16(a.s, b.s, acc[nt], 0, 0, 0);
        }
    }
    // C/D: col = lane&15, row = quad*4 + reg
    const int rowbase = blockIdx.x * 64 + wave * 16 + quad * 4;
#pragma unroll
    for (int nt = 0; nt < 8; ++nt) {
#pragma unroll
        for (int r = 0; r < 4; ++r) {
            const int rr = rowbase + r;
            if (rr < NN) xwh[(size_t)rr * NH + nt * 16 + mcol] = f2bf(acc[nt][r]);
        }
    }
}

// ======================= CSR build: pass 1 histogram ======================
__global__ __launch_bounds__(256) void p1hist_k(const int* __restrict__ edst,
                                                int* __restrict__ hmat) {
    __shared__ uint h[NBUCK];
    for (int i = threadIdx.x; i < NBUCK; i += 256) h[i] = 0;
    __syncthreads();
    const int b = blockIdx.x;
    const int e0 = b * CH, e1 = min(NE, e0 + CH);
    for (int e = e0 + threadIdx.x; e < e1; e += 256)
        atomicAdd(&h[((uint)edst[e]) >> 7], 1u);
    __syncthreads();
    for (int i = threadIdx.x; i < NBUCK; i += 256)
        hmat[(size_t)i * NBLK + b] = (int)h[i];
}

// ======================= scan of hmat (306K ints) =========================
__global__ __launch_bounds__(512) void hscan1_k(int* __restrict__ hmat,
                                                int* __restrict__ partials) {
    __shared__ int s[512];
    const int t = threadIdx.x;
    const int i = blockIdx.x * 512 + t;
    const int v = (i < HTOT) ? hmat[i] : 0;
    s[t] = v;
    __syncthreads();
#pragma unroll
    for (int off = 1; off < 512; off <<= 1) {
        int a = (t >= off) ? s[t - off] : 0;
        __syncthreads();
        s[t] += a;
        __syncthreads();
    }
    if (i < HTOT) hmat[i] = s[t] - v;
    if (t == 511) partials[blockIdx.x] = s[t];
}

__global__ __launch_bounds__(1024) void hscan2_k(int* __restrict__ partials, int nb) {
    __shared__ int s[1024];
    const int t = threadIdx.x;
    const int v = (t < nb) ? partials[t] : 0;
    s[t] = v;
    __syncthreads();
#pragma unroll
    for (int off = 1; off < 1024; off <<= 1) {
        int a = (t >= off) ? s[t - off] : 0;
        __syncthreads();
        s[t] += a;
        __syncthreads();
    }
    if (t < nb) partials[t] = s[t] - v;
}

__global__ __launch_bounds__(512) void hscan3_k(int* __restrict__ hmat,
                                                const int* __restrict__ partials) {
    const int i = blockIdx.x * 512 + threadIdx.x;
    if (i < HTOT) hmat[i] += partials[blockIdx.x];
}

// ======================= pass 1 scatter (block-private ranges) ============
__global__ __launch_bounds__(256) void p1scat_k(const int* __restrict__ esrc,
                                                const int* __restrict__ edst,
                                                const float* __restrict__ ew,
                                                const int* __restrict__ hmat,
                                                uint2* __restrict__ ep1) {
    __shared__ uint base[NBUCK];
    const int b = blockIdx.x;
    for (int i = threadIdx.x; i < NBUCK; i += 256)
        base[i] = (uint)hmat[(size_t)i * NBLK + b];
    __syncthreads();
    const int e0 = b * CH, e1 = min(NE, e0 + CH);
    for (int e = e0 + threadIdx.x; e < e1; e += 256) {
        const uint d = (uint)edst[e];
        const uint pos = atomicAdd(&base[d >> 7], 1u);
        ep1[pos] = make_uint2((uint)esrc[e] | ((d & 127u) << 17), __float_as_uint(ew[e]));
    }
}

// ======================= pass 2: in-bucket sort -> CSR + rp ===============
__global__ __launch_bounds__(256) void p2_k(const int* __restrict__ hmat,
                                            const uint2* __restrict__ ep1,
                                            uint2* __restrict__ ep,
                                            int* __restrict__ rp) {
    const int bk = blockIdx.x;
    const int beg = hmat[(size_t)bk * NBLK];
    const int end = (bk == NBUCK - 1) ? NE : hmat[(size_t)(bk + 1) * NBLK];
    __shared__ uint cnt[128];
    __shared__ uint st[128];
    if (threadIdx.x < 128) cnt[threadIdx.x] = 0;
    __syncthreads();
    for (int j = beg + threadIdx.x; j < end; j += 256)
        atomicAdd(&cnt[(ep1[j].x >> 17) & 127u], 1u);
    __syncthreads();
    if (threadIdx.x < 128) st[threadIdx.x] = cnt[threadIdx.x];
    __syncthreads();
#pragma unroll
    for (int off = 1; off < 128; off <<= 1) {
        uint a = 0;
        if (threadIdx.x < 128 && threadIdx.x >= off) a = st[threadIdx.x - off];
        __syncthreads();
        if (threadIdx.x < 128) st[threadIdx.x] += a;
        __syncthreads();
    }
    if (threadIdx.x < 128) {
        const uint start = st[threadIdx.x] - cnt[threadIdx.x];
        const int d = bk * 128 + threadIdx.x;
        if (d < NN) rp[d] = beg + (int)start;
        cnt[threadIdx.x] = (uint)beg + start;
    }
    if (bk == 0 && threadIdx.x == 200) rp[NN] = NE;
    __syncthreads();
    for (int j = beg + threadIdx.x; j < end; j += 256) {
        const uint2 r = ep1[j];
        const uint pos = atomicAdd(&cnt[(r.x >> 17) & 127u], 1u);
        ep[pos] = r;
    }
}

// ============================ SpMM1 gather (bf16) =========================
__global__ __launch_bounds__(256) void spmm1_g(const int* __restrict__ rp,
                                               const uint2* __restrict__ ep,
                                               const uint* __restrict__ xwb,
                                               float2* __restrict__ hacc2) {
    const int n = blockIdx.x * 4 + (threadIdx.x >> 6);
    const int t = threadIdx.x & 63;
    const int beg = rp[n], end = rp[n + 1];
    float a0 = 0.f, a1 = 0.f;
    int j = beg;
    for (; j + 3 < end; j += 4) {
        const uint2 e0 = ep[j], e1 = ep[j + 1], e2 = ep[j + 2], e3 = ep[j + 3];
        const uint v0 = xwb[(size_t)(e0.x & 0x1FFFFu) * 64 + t];
        const uint v1 = xwb[(size_t)(e1.x & 0x1FFFFu) * 64 + t];
        const uint v2 = xwb[(size_t)(e2.x & 0x1FFFFu) * 64 + t];
        const uint v3 = xwb[(size_t)(e3.x & 0x1FFFFu) * 64 + t];
        const float w0 = __uint_as_float(e0.y), w1 = __uint_as_float(e1.y);
        const float w2 = __uint_as_float(e2.y), w3 = __uint_as_float(e3.y);
        a0 = fmaf(w0, bflo(v0), a0); a1 = fmaf(w0, bfhi(v0), a1);
        a0 = fmaf(w1, bflo(v1), a0); a1 = fmaf(w1, bfhi(v1), a1);
        a0 = fmaf(w2, bflo(v2), a0); a1 = fmaf(w2, bfhi(v2), a1);
        a0 = fmaf(w3, bflo(v3), a0); a1 = fmaf(w3, bfhi(v3), a1);
    }
    for (; j < end; ++j) {
        const uint2 e = ep[j];
        const uint v = xwb[(size_t)(e.x & 0x1FFFFu) * 64 + t];
        const float w = __uint_as_float(e.y);
        a0 = fmaf(w, bflo(v), a0); a1 = fmaf(w, bfhi(v), a1);
    }
    hacc2[(size_t)n * 64 + t] = make_float2(a0, a1);
}

// ============================ SpMM2 gather (bf16) =========================
__global__ __launch_bounds__(320) void spmm2_g(const int* __restrict__ rp,
                                               const uint2* __restrict__ ep,
                                               const uint* __restrict__ hwb,
                                               float2* __restrict__ z2) {
    const int n = blockIdx.x * 16 + threadIdx.x / 20;
    const int t = threadIdx.x % 20;
    const int beg = rp[n], end = rp[n + 1];
    float a0 = 0.f, a1 = 0.f;
    int j = beg;
    for (; j + 3 < end; j += 4) {
        const uint2 e0 = ep[j], e1 = ep[j + 1], e2 = ep[j + 2], e3 = ep[j + 3];
        const uint v0 = hwb[(size_t)(e0.x & 0x1FFFFu) * 20 + t];
        const uint v1 = hwb[(size_t)(e1.x & 0x1FFFFu) * 20 + t];
        const uint v2 = hwb[(size_t)(e2.x & 0x1FFFFu) * 20 + t];
        const uint v3 = hwb[(size_t)(e3.x & 0x1FFFFu) * 20 + t];
        const float w0 = __uint_as_float(e0.y), w1 = __uint_as_float(e1.y);
        const float w2 = __uint_as_float(e2.y), w3 = __uint_as_float(e3.y);
        a0 = fmaf(w0, bflo(v0), a0); a1 = fmaf(w0, bfhi(v0), a1);
        a0 = fmaf(w1, bflo(v1), a0); a1 = fmaf(w1, bfhi(v1), a1);
        a0 = fmaf(w2, bflo(v2), a0); a1 = fmaf(w2, bfhi(v2), a1);
        a0 = fmaf(w3, bflo(v3), a0); a1 = fmaf(w3, bfhi(v3), a1);
    }
    for (; j < end; ++j) {
        const uint2 e = ep[j];
        const uint v = hwb[(size_t)(e.x & 0x1FFFFu) * 20 + t];
        const float w = __uint_as_float(e.y);
        a0 = fmaf(w, bflo(v), a0); a1 = fmaf(w, bfhi(v), a1);
    }
    z2[(size_t)n * 20 + t] = make_float2(a0, a1);
}

// ============================ pointwise ===================================
__global__ __launch_bounds__(128) void norm_k(float* __restrict__ h,
                                              const float* __restrict__ b0) {
    const int n = blockIdx.x;
    const int f = threadIdx.x;
    const float v = h[(size_t)n * NH + f] + b0[f];
    float s = v * v;
#pragma unroll
    for (int o = 32; o > 0; o >>= 1) s += __shfl_down(s, o, 64);
    __shared__ float wsum[2];
    if ((threadIdx.x & 63) == 0) wsum[threadIdx.x >> 6] = s;
    __syncthreads();
    const float nrm = sqrtf(wsum[0] + wsum[1]);
    const float scale = 1.0f / fmaxf(nrm, 1e-12f);
    h[(size_t)n * NH + f] = fmaxf(v * scale, 0.0f);
}

__global__ void gemm2_k(const float* __restrict__ h2,
                        const float* __restrict__ W1,
                        unsigned short* __restrict__ hwh) {
    __shared__ float sW1[NH * NC];
    const int lt = threadIdx.y * NC + threadIdx.x;
    for (int i = lt; i < NH * NC; i += 240) sW1[i] = W1[i];
    __syncthreads();
    const int n = blockIdx.x * 6 + threadIdx.y;
    if (n >= NN) return;
    const int f = threadIdx.x;
    const float* hr = h2 + (size_t)n * NH;
    float acc = 0.f;
#pragma unroll 4
    for (int k = 0; k < NH; k += 4) {
        const float4 hv = *(const float4*)(hr + k);
        acc = fmaf(hv.x, sW1[(k + 0) * NC + f], acc);
        acc = fmaf(hv.y, sW1[(k + 1) * NC + f], acc);
        acc = fmaf(hv.z, sW1[(k + 2) * NC + f], acc);
        acc = fmaf(hv.w, sW1[(k + 3) * NC + f], acc);
    }
    hwh[(size_t)n * NC + f] = f2bf(acc);
}

__global__ __launch_bounds__(256) void lsm_k(float* __restrict__ z,
                                             const float* __restrict__ b1) {
    const int wave = threadIdx.x >> 6;
    const int lane = threadIdx.x & 63;
    const int n = blockIdx.x * 4 + wave;
    float v = -INFINITY;
    if (lane < NC) v = z[(size_t)n * NC + lane] + b1[lane];
    float m = v;
#pragma unroll
    for (int o = 32; o > 0; o >>= 1) m = fmaxf(m, __shfl_down(m, o, 64));
    m = __shfl(m, 0, 64);
    float ex = (lane < NC) ? expf(v - m) : 0.0f;
#pragma unroll
    for (int o = 32; o > 0; o >>= 1) ex += __shfl_down(ex, o, 64);
    const float lse = logf(__shfl(ex, 0, 64));
    if (lane < NC) z[(size_t)n * NC + lane] = v - m - lse;
}

// ============================ launch ======================================
extern "C" void kernel_launch(void* const* d_in, const int* in_sizes, int n_in,
                              void* d_out, int out_size, void* d_ws, size_t ws_size,
                              hipStream_t stream) {
    const float* x    = (const float*)d_in[0];
    const int*   esrc = (const int*)d_in[1];
    const int*   edst = (const int*)d_in[2];
    const float* ew   = (const float*)d_in[3];
    const float* W0   = (const float*)d_in[4];
    const float* b0   = (const float*)d_in[5];
    const float* W1   = (const float*)d_in[6];
    const float* b1   = (const float*)d_in[7];
    float* out = (float*)d_out;

    // workspace layout (4-byte words); uint2/uint4 arrays at even word offsets.
    size_t o = 0;
    uint*  xwb  = (uint*)d_ws + o;  o += (size_t)NN * 64;        // 25.6 MB
    float* hacc = (float*)d_ws + o; o += (size_t)NN * NH;        // 51.2 MB (ep1 aliases)
    uint2* ep1  = (uint2*)hacc;
    uint*  hwb  = (uint*)d_ws + o;  o += (size_t)NN * 20;        //  8.0 MB
    uint2* ep   = (uint2*)((uint*)d_ws + o); o += (size_t)NE * 2; // 25.6 MB
    int*   hmat = (int*)d_ws + o;   o += HTOT;                   //  1.2 MB
    int*   rp   = (int*)d_ws + o;   o += NN + 2;
    int*   partials = (int*)d_ws + o; o += 1024;
    if (o & 1) o += 1;
    uint4* W0p  = (uint4*)((uint*)d_ws + o); o += 16384;         // 64 KB packed W0

    // 1. pack W0 into B-fragment order, then xw = bf16(x @ W0) via MFMA
    w0pack_k<<<16, 256, 0, stream>>>(W0, W0p);
    gemm1_mfma<<<(NN + 63) / 64, 256, 0, stream>>>(x, W0p, (unsigned short*)xwb);

    // 2. CSR build: two-pass counting sort, block-private write ranges
    p1hist_k<<<NBLK, 256, 0, stream>>>(edst, hmat);
    hscan1_k<<<HS1, 512, 0, stream>>>(hmat, partials);
    hscan2_k<<<1, 1024, 0, stream>>>(partials, HS1);
    hscan3_k<<<HS1, 512, 0, stream>>>(hmat, partials);
    p1scat_k<<<NBLK, 256, 0, stream>>>(esrc, edst, ew, hmat, ep1);
    p2_k<<<NBUCK, 256, 0, stream>>>(hmat, ep1, ep, rp);

    // 3. hacc = gather-spmm(xw)   (overwrites ep1 region — ep1 dead now)
    spmm1_g<<<NN / 4, 256, 0, stream>>>(rp, ep, xwb, (float2*)hacc);
    // 4. h2 = relu(l2norm(hacc + b0)) in place
    norm_k<<<NN, 128, 0, stream>>>(hacc, b0);
    // 5. hw = bf16(h2 @ W1)
    gemm2_k<<<(NN + 5) / 6, dim3(40, 6), 0, stream>>>(hacc, W1, (unsigned short*)hwb);
    // 6. z = gather-spmm(hw) into d_out
    spmm2_g<<<NN / 16, 320, 0, stream>>>(rp, ep, hwb, (float2*)out);
    // 7. log_softmax(z + b1) in place
    lsm_k<<<NN / 4, 256, 0, stream>>>(out, b1);
}

// Round 6
// 580.400 us; speedup vs baseline: 4.1255x; 1.1115x over previous
//
#include <hip/hip_runtime.h>
#include <math.h>

#define NN 100000
#define NE 3200000
#define NF 256
#define NH 128
#define NC 40

#define CH 8192                    // edges per pass-1 block
#define NBLK 391                   // ceil(NE/CH)
#define NBUCK 782                  // ceil(NN/128) buckets of 128 dsts
#define HTOT (NBUCK * NBLK)        // 305762
#define HS1 ((HTOT + 511) / 512)   // 598 scan blocks
#define NTILE 1563                 // ceil(NN/64) gemm1 row tiles

typedef unsigned int uint;
typedef short short8 __attribute__((ext_vector_type(8)));
typedef float floatx4 __attribute__((ext_vector_type(4)));

// ---- bf16 helpers (manual, RNE) ------------------------------------------
__device__ __forceinline__ float bflo(uint v) { return __uint_as_float(v << 16); }
__device__ __forceinline__ float bfhi(uint v) { return __uint_as_float(v & 0xffff0000u); }
__device__ __forceinline__ unsigned short f2bf(float f) {
    const uint u = __float_as_uint(f);
    return (unsigned short)((u + 0x7fffu + ((u >> 16) & 1u)) >> 16);
}
__device__ __forceinline__ uint pack2bf(float a, float b) {
    return (uint)f2bf(a) | ((uint)f2bf(b) << 16);
}

union ABfrag { uint u[4]; short8 s; };

// ================= W0 pre-pack into MFMA B-fragment order =================
__global__ __launch_bounds__(256) void w0pack_k(const float* __restrict__ W0,
                                                uint4* __restrict__ W0p) {
    const int idx = blockIdx.x * 256 + threadIdx.x;  // 4096 entries
    if (idx >= 4096) return;
    const int lane  = idx & 63;
    const int ntile = (idx >> 6) & 7;
    const int kstep = idx >> 9;
    const int n  = ntile * 16 + (lane & 15);
    const int kb = kstep * 32 + (lane >> 4) * 8;
    uint w[4];
#pragma unroll
    for (int ww = 0; ww < 4; ++ww)
        w[ww] = pack2bf(W0[(size_t)(kb + 2 * ww) * NH + n],
                        W0[(size_t)(kb + 2 * ww + 1) * NH + n]);
    W0p[idx] = make_uint4(w[0], w[1], w[2], w[3]);
}

// ============================ GEMM1 (MFMA bf16) ===========================
// grid-stride over 64-row tiles; W0p staged in LDS once per block.
__global__ __launch_bounds__(256) void gemm1_mfma(const float* __restrict__ x,
                                                  const uint4* __restrict__ W0p,
                                                  unsigned short* __restrict__ xwh) {
    __shared__ __align__(16) uint4 sB[4096];  // 64 KB: [kstep][ntile][lane]
    for (int i = threadIdx.x; i < 4096; i += 256) sB[i] = W0p[i];
    __syncthreads();

    const int wave = threadIdx.x >> 6;
    const int lane = threadIdx.x & 63;
    const int quad = lane >> 4;
    const int mcol = lane & 15;

    for (int tile = blockIdx.x; tile < NTILE; tile += 512) {
        const int row  = tile * 64 + wave * 16 + mcol;
        const int rowc = min(row, NN - 1);
        const float* xr = x + (size_t)rowc * NF + quad * 8;

        floatx4 acc[8] = {};
        float4 lo = *(const float4*)(xr);
        float4 hi = *(const float4*)(xr + 4);
#pragma unroll
        for (int ks = 0; ks < 8; ++ks) {
            ABfrag a;
            a.u[0] = pack2bf(lo.x, lo.y);
            a.u[1] = pack2bf(lo.z, lo.w);
            a.u[2] = pack2bf(hi.x, hi.y);
            a.u[3] = pack2bf(hi.z, hi.w);
            if (ks < 7) {
                lo = *(const float4*)(xr + (ks + 1) * 32);
                hi = *(const float4*)(xr + (ks + 1) * 32 + 4);
            }
#pragma unroll
            for (int nt = 0; nt < 8; ++nt) {
                ABfrag b;
                const uint4 bw = sB[(ks * 8 + nt) * 64 + lane];
                b.u[0] = bw.x; b.u[1] = bw.y; b.u[2] = bw.z; b.u[3] = bw.w;
                acc[nt] = __builtin_amdgcn_mfma_f32_16x16x32_bf16(a.s, b.s, acc[nt], 0, 0, 0);
            }
        }
        const int rowbase = tile * 64 + wave * 16 + quad * 4;
#pragma unroll
        for (int nt = 0; nt < 8; ++nt) {
#pragma unroll
            for (int r = 0; r < 4; ++r) {
                const int rr = rowbase + r;
                if (rr < NN) xwh[(size_t)rr * NH + nt * 16 + mcol] = f2bf(acc[nt][r]);
            }
        }
    }
}

// ======================= CSR build: pass 1 histogram ======================
__global__ __launch_bounds__(256) void p1hist_k(const int* __restrict__ edst,
                                                int* __restrict__ hmat) {
    __shared__ uint h[NBUCK];
    for (int i = threadIdx.x; i < NBUCK; i += 256) h[i] = 0;
    __syncthreads();
    const int b = blockIdx.x;
    const int e0 = b * CH, e1 = min(NE, e0 + CH);
    for (int e = e0 + threadIdx.x; e < e1; e += 256)
        atomicAdd(&h[((uint)edst[e]) >> 7], 1u);
    __syncthreads();
    for (int i = threadIdx.x; i < NBUCK; i += 256)
        hmat[(size_t)i * NBLK + b] = (int)h[i];
}

// ======================= scan of hmat (306K ints) =========================
__global__ __launch_bounds__(512) void hscan1_k(int* __restrict__ hmat,
                                                int* __restrict__ partials) {
    __shared__ int s[512];
    const int t = threadIdx.x;
    const int i = blockIdx.x * 512 + t;
    const int v = (i < HTOT) ? hmat[i] : 0;
    s[t] = v;
    __syncthreads();
#pragma unroll
    for (int off = 1; off < 512; off <<= 1) {
        int a = (t >= off) ? s[t - off] : 0;
        __syncthreads();
        s[t] += a;
        __syncthreads();
    }
    if (i < HTOT) hmat[i] = s[t] - v;
    if (t == 511) partials[blockIdx.x] = s[t];
}

__global__ __launch_bounds__(1024) void hscan2_k(int* __restrict__ partials, int nb) {
    __shared__ int s[1024];
    const int t = threadIdx.x;
    const int v = (t < nb) ? partials[t] : 0;
    s[t] = v;
    __syncthreads();
#pragma unroll
    for (int off = 1; off < 1024; off <<= 1) {
        int a = (t >= off) ? s[t - off] : 0;
        __syncthreads();
        s[t] += a;
        __syncthreads();
    }
    if (t < nb) partials[t] = s[t] - v;
}

__global__ __launch_bounds__(512) void hscan3_k(int* __restrict__ hmat,
                                                const int* __restrict__ partials) {
    const int i = blockIdx.x * 512 + threadIdx.x;
    if (i < HTOT) hmat[i] += partials[blockIdx.x];
}

// ======================= pass 1 scatter (block-private ranges) ============
__global__ __launch_bounds__(256) void p1scat_k(const int* __restrict__ esrc,
                                                const int* __restrict__ edst,
                                                const float* __restrict__ ew,
                                                const int* __restrict__ hmat,
                                                uint2* __restrict__ ep1) {
    __shared__ uint base[NBUCK];
    const int b = blockIdx.x;
    for (int i = threadIdx.x; i < NBUCK; i += 256)
        base[i] = (uint)hmat[(size_t)i * NBLK + b];
    __syncthreads();
    const int e0 = b * CH, e1 = min(NE, e0 + CH);
    for (int e = e0 + threadIdx.x; e < e1; e += 256) {
        const uint d = (uint)edst[e];
        const uint pos = atomicAdd(&base[d >> 7], 1u);
        ep1[pos] = make_uint2((uint)esrc[e] | ((d & 127u) << 17), __float_as_uint(ew[e]));
    }
}

// ======================= pass 2: in-bucket sort -> CSR + rp ===============
__global__ __launch_bounds__(256) void p2_k(const int* __restrict__ hmat,
                                            const uint2* __restrict__ ep1,
                                            uint2* __restrict__ ep,
                                            int* __restrict__ rp) {
    const int bk = blockIdx.x;
    const int beg = hmat[(size_t)bk * NBLK];
    const int end = (bk == NBUCK - 1) ? NE : hmat[(size_t)(bk + 1) * NBLK];
    __shared__ uint cnt[128];
    __shared__ uint st[128];
    if (threadIdx.x < 128) cnt[threadIdx.x] = 0;
    __syncthreads();
    for (int j = beg + threadIdx.x; j < end; j += 256)
        atomicAdd(&cnt[(ep1[j].x >> 17) & 127u], 1u);
    __syncthreads();
    if (threadIdx.x < 128) st[threadIdx.x] = cnt[threadIdx.x];
    __syncthreads();
#pragma unroll
    for (int off = 1; off < 128; off <<= 1) {
        uint a = 0;
        if (threadIdx.x < 128 && threadIdx.x >= off) a = st[threadIdx.x - off];
        __syncthreads();
        if (threadIdx.x < 128) st[threadIdx.x] += a;
        __syncthreads();
    }
    if (threadIdx.x < 128) {
        const uint start = st[threadIdx.x] - cnt[threadIdx.x];
        const int d = bk * 128 + threadIdx.x;
        if (d < NN) rp[d] = beg + (int)start;
        cnt[threadIdx.x] = (uint)beg + start;
    }
    if (bk == 0 && threadIdx.x == 200) rp[NN] = NE;
    __syncthreads();
    for (int j = beg + threadIdx.x; j < end; j += 256) {
        const uint2 r = ep1[j];
        const uint pos = atomicAdd(&cnt[(r.x >> 17) & 127u], 1u);
        ep[pos] = r;
    }
}

// ================ SpMM1 + bias + L2norm + ReLU -> bf16 h2 =================
// one wave per node; lane t holds feats {2t,2t+1}; 8-edge unroll.
__global__ __launch_bounds__(256) void spmm1n_g(const int* __restrict__ rp,
                                                const uint2* __restrict__ ep,
                                                const uint* __restrict__ xwb,
                                                const float* __restrict__ b0,
                                                uint* __restrict__ h2b) {
    const int n = blockIdx.x * 4 + (threadIdx.x >> 6);
    const int t = threadIdx.x & 63;
    const int beg = rp[n], end = rp[n + 1];
    float a0 = 0.f, a1 = 0.f;
    int j = beg;
    for (; j + 7 < end; j += 8) {
        uint2 e[8];
        uint v[8];
#pragma unroll
        for (int u = 0; u < 8; ++u) e[u] = ep[j + u];
#pragma unroll
        for (int u = 0; u < 8; ++u) v[u] = xwb[(size_t)(e[u].x & 0x1FFFFu) * 64 + t];
#pragma unroll
        for (int u = 0; u < 8; ++u) {
            const float w = __uint_as_float(e[u].y);
            a0 = fmaf(w, bflo(v[u]), a0);
            a1 = fmaf(w, bfhi(v[u]), a1);
        }
    }
    for (; j < end; ++j) {
        const uint2 e = ep[j];
        const uint v = xwb[(size_t)(e.x & 0x1FFFFu) * 64 + t];
        const float w = __uint_as_float(e.y);
        a0 = fmaf(w, bflo(v), a0); a1 = fmaf(w, bfhi(v), a1);
    }
    // bias + L2 normalize (wave butterfly) + ReLU, store bf16
    const float2 bb = *(const float2*)(b0 + 2 * t);
    const float v0 = a0 + bb.x, v1 = a1 + bb.y;
    float s = v0 * v0 + v1 * v1;
#pragma unroll
    for (int o = 1; o < 64; o <<= 1) s += __shfl_xor(s, o, 64);
    const float scale = 1.0f / fmaxf(sqrtf(s), 1e-12f);
    h2b[(size_t)n * 64 + t] = pack2bf(fmaxf(v0 * scale, 0.0f), fmaxf(v1 * scale, 0.0f));
}

// ==================== GEMM2 (bf16 in, bf16 out) ===========================
__global__ void gemm2_k(const uint* __restrict__ h2b,
                        const float* __restrict__ W1,
                        unsigned short* __restrict__ hwh) {
    __shared__ float sW1[NH * NC];
    const int lt = threadIdx.y * NC + threadIdx.x;
    for (int i = lt; i < NH * NC; i += 240) sW1[i] = W1[i];
    __syncthreads();
    const int n = blockIdx.x * 6 + threadIdx.y;
    if (n >= NN) return;
    const int f = threadIdx.x;
    const uint* hr = h2b + (size_t)n * 64;
    float acc = 0.f;
#pragma unroll 4
    for (int k8 = 0; k8 < 16; ++k8) {
        const uint4 hv = *(const uint4*)(hr + k8 * 4);
        const int kb = k8 * 8;
        acc = fmaf(bflo(hv.x), sW1[(kb + 0) * NC + f], acc);
        acc = fmaf(bfhi(hv.x), sW1[(kb + 1) * NC + f], acc);
        acc = fmaf(bflo(hv.y), sW1[(kb + 2) * NC + f], acc);
        acc = fmaf(bfhi(hv.y), sW1[(kb + 3) * NC + f], acc);
        acc = fmaf(bflo(hv.z), sW1[(kb + 4) * NC + f], acc);
        acc = fmaf(bfhi(hv.z), sW1[(kb + 5) * NC + f], acc);
        acc = fmaf(bflo(hv.w), sW1[(kb + 6) * NC + f], acc);
        acc = fmaf(bfhi(hv.w), sW1[(kb + 7) * NC + f], acc);
    }
    hwh[(size_t)n * NC + f] = f2bf(acc);
}

// ============== SpMM2 + bias + log_softmax (fused epilogue) ===============
// 20 threads per node (feats packed 2/lane), 16 nodes per 320-block.
__global__ __launch_bounds__(320) void spmm2l_g(const int* __restrict__ rp,
                                                const uint2* __restrict__ ep,
                                                const uint* __restrict__ hwb,
                                                const float* __restrict__ b1,
                                                float2* __restrict__ out2) {
    const int nl = threadIdx.x / 20;          // local node 0..15
    const int g  = threadIdx.x % 20;
    const int n  = blockIdx.x * 16 + nl;
    const int beg = rp[n], end = rp[n + 1];
    float a0 = 0.f, a1 = 0.f;
    int j = beg;
    for (; j + 7 < end; j += 8) {
        uint2 e[8];
        uint v[8];
#pragma unroll
        for (int u = 0; u < 8; ++u) e[u] = ep[j + u];
#pragma unroll
        for (int u = 0; u < 8; ++u) v[u] = hwb[(size_t)(e[u].x & 0x1FFFFu) * 20 + g];
#pragma unroll
        for (int u = 0; u < 8; ++u) {
            const float w = __uint_as_float(e[u].y);
            a0 = fmaf(w, bflo(v[u]), a0);
            a1 = fmaf(w, bfhi(v[u]), a1);
        }
    }
    for (; j < end; ++j) {
        const uint2 e = ep[j];
        const uint v = hwb[(size_t)(e.x & 0x1FFFFu) * 20 + g];
        const float w = __uint_as_float(e.y);
        a0 = fmaf(w, bflo(v), a0); a1 = fmaf(w, bfhi(v), a1);
    }
    const float2 bb = *(const float2*)(b1 + 2 * g);
    a0 += bb.x; a1 += bb.y;
    // log_softmax over the node's 40 values (20 threads x 2)
    __shared__ float red[16 * 20];
    __shared__ float stat[16];
    red[nl * 20 + g] = fmaxf(a0, a1);
    __syncthreads();
    if (g == 0) {
        float m = -INFINITY;
#pragma unroll
        for (int q = 0; q < 20; ++q) m = fmaxf(m, red[nl * 20 + q]);
        stat[nl] = m;
    }
    __syncthreads();
    const float m = stat[nl];
    red[nl * 20 + g] = expf(a0 - m) + expf(a1 - m);
    __syncthreads();
    if (g == 0) {
        float ssum = 0.f;
#pragma unroll
        for (int q = 0; q < 20; ++q) ssum += red[nl * 20 + q];
        stat[nl] = logf(ssum);
    }
    __syncthreads();
    const float lse = stat[nl];
    out2[(size_t)n * 20 + g] = make_float2(a0 - m - lse, a1 - m - lse);
}

// ============================ launch ======================================
extern "C" void kernel_launch(void* const* d_in, const int* in_sizes, int n_in,
                              void* d_out, int out_size, void* d_ws, size_t ws_size,
                              hipStream_t stream) {
    const float* x    = (const float*)d_in[0];
    const int*   esrc = (const int*)d_in[1];
    const int*   edst = (const int*)d_in[2];
    const float* ew   = (const float*)d_in[3];
    const float* W0   = (const float*)d_in[4];
    const float* b0   = (const float*)d_in[5];
    const float* W1   = (const float*)d_in[6];
    const float* b1   = (const float*)d_in[7];
    float* out = (float*)d_out;

    // workspace layout (4-byte words); uint2/uint4 arrays at even word offsets.
    size_t o = 0;
    uint*  xwb  = (uint*)d_ws + o;  o += (size_t)NN * 64;         // 25.6 MB
    uint*  h2b  = (uint*)d_ws + o;  o += (size_t)NN * 64;         // 25.6 MB (ep1 aliases)
    uint2* ep1  = (uint2*)h2b;                                    // dead before h2b written
    uint*  hwb  = (uint*)d_ws + o;  o += (size_t)NN * 20;         //  8.0 MB
    uint2* ep   = (uint2*)((uint*)d_ws + o); o += (size_t)NE * 2; // 25.6 MB
    int*   hmat = (int*)d_ws + o;   o += HTOT;                    //  1.2 MB
    int*   rp   = (int*)d_ws + o;   o += NN + 2;
    int*   partials = (int*)d_ws + o; o += 1024;
    if (o & 3) o += 4 - (o & 3);
    uint4* W0p  = (uint4*)((uint*)d_ws + o); o += 16384;          // 64 KB packed W0

    // 1. pack W0; xw = bf16(x @ W0) via MFMA
    w0pack_k<<<16, 256, 0, stream>>>(W0, W0p);
    gemm1_mfma<<<512, 256, 0, stream>>>(x, W0p, (unsigned short*)xwb);

    // 2. CSR build: two-pass counting sort, block-private write ranges
    p1hist_k<<<NBLK, 256, 0, stream>>>(edst, hmat);
    hscan1_k<<<HS1, 512, 0, stream>>>(hmat, partials);
    hscan2_k<<<1, 1024, 0, stream>>>(partials, HS1);
    hscan3_k<<<HS1, 512, 0, stream>>>(hmat, partials);
    p1scat_k<<<NBLK, 256, 0, stream>>>(esrc, edst, ew, hmat, ep1);
    p2_k<<<NBUCK, 256, 0, stream>>>(hmat, ep1, ep, rp);

    // 3. h2 = relu(l2norm(spmm(xw) + b0)) as bf16   (overwrites ep1 — dead)
    spmm1n_g<<<NN / 4, 256, 0, stream>>>(rp, ep, xwb, b0, h2b);
    // 4. hw = bf16(h2 @ W1)
    gemm2_k<<<(NN + 5) / 6, dim3(40, 6), 0, stream>>>(h2b, W1, (unsigned short*)hwb);
    // 5. out = log_softmax(spmm(hw) + b1)
    spmm2l_g<<<NN / 16, 320, 0, stream>>>(rp, ep, hwb, b1, (float2*)out);
}

// Round 7
// 514.124 us; speedup vs baseline: 4.6573x; 1.1289x over previous
//
#include <hip/hip_runtime.h>
#include <math.h>

#define NN 100000
#define NE 3200000
#define NF 256
#define NH 128
#define NC 40

#define CH 8192                    // edges per pass-1 block
#define NBLK 391                   // ceil(NE/CH)
#define NBUCK 782                  // ceil(NN/128) buckets of 128 dsts
#define HTOT (NBUCK * NBLK)        // 305762
#define HS1 ((HTOT + 511) / 512)   // 598 scan blocks
#define NTILE 1563                 // ceil(NN/64) gemm row tiles

typedef unsigned int uint;
typedef short short8 __attribute__((ext_vector_type(8)));
typedef float floatx4 __attribute__((ext_vector_type(4)));

// ---- bf16 helpers (manual, RNE) ------------------------------------------
__device__ __forceinline__ float bflo(uint v) { return __uint_as_float(v << 16); }
__device__ __forceinline__ float bfhi(uint v) { return __uint_as_float(v & 0xffff0000u); }
__device__ __forceinline__ unsigned short f2bf(float f) {
    const uint u = __float_as_uint(f);
    return (unsigned short)((u + 0x7fffu + ((u >> 16) & 1u)) >> 16);
}
__device__ __forceinline__ uint pack2bf(float a, float b) {
    return (uint)f2bf(a) | ((uint)f2bf(b) << 16);
}

union ABfrag { uint u[4]; short8 s; };

// ========== pack W0 (4096 frags) and W1 (768 frags, zero-padded) ==========
// B-frag: n = ntile*16 + (lane&15), k = kstep*32 + (lane>>4)*8 + j
__global__ __launch_bounds__(256) void prep_pack_k(const float* __restrict__ W0,
                                                   const float* __restrict__ W1,
                                                   uint4* __restrict__ W0p,
                                                   uint4* __restrict__ W1p) {
    const int idx = blockIdx.x * 256 + threadIdx.x;
    if (idx < 4096) {  // W0: [kstep 0..7][ntile 0..7][lane]
        const int lane  = idx & 63;
        const int ntile = (idx >> 6) & 7;
        const int kstep = idx >> 9;
        const int n  = ntile * 16 + (lane & 15);
        const int kb = kstep * 32 + (lane >> 4) * 8;
        uint w[4];
#pragma unroll
        for (int ww = 0; ww < 4; ++ww)
            w[ww] = pack2bf(W0[(size_t)(kb + 2 * ww) * NH + n],
                            W0[(size_t)(kb + 2 * ww + 1) * NH + n]);
        W0p[idx] = make_uint4(w[0], w[1], w[2], w[3]);
    } else if (idx < 4096 + 768) {  // W1: [kstep 0..3][ntile 0..2][lane]
        const int i2 = idx - 4096;
        const int lane  = i2 & 63;
        const int ntile = (i2 >> 6) % 3;
        const int kstep = (i2 >> 6) / 3;
        const int n  = ntile * 16 + (lane & 15);
        const int kb = kstep * 32 + (lane >> 4) * 8;
        uint w[4];
#pragma unroll
        for (int ww = 0; ww < 4; ++ww) {
            const float lo = (n < NC) ? W1[(size_t)(kb + 2 * ww) * NC + n] : 0.0f;
            const float hi = (n < NC) ? W1[(size_t)(kb + 2 * ww + 1) * NC + n] : 0.0f;
            w[ww] = pack2bf(lo, hi);
        }
        W1p[i2] = make_uint4(w[0], w[1], w[2], w[3]);
    }
}

// ============================ GEMM1 (MFMA bf16) ===========================
__global__ __launch_bounds__(256) void gemm1_mfma(const float* __restrict__ x,
                                                  const uint4* __restrict__ W0p,
                                                  unsigned short* __restrict__ xwh) {
    __shared__ __align__(16) uint4 sB[4096];  // 64 KB
    for (int i = threadIdx.x; i < 4096; i += 256) sB[i] = W0p[i];
    __syncthreads();

    const int wave = threadIdx.x >> 6;
    const int lane = threadIdx.x & 63;
    const int quad = lane >> 4;
    const int mcol = lane & 15;

    for (int tile = blockIdx.x; tile < NTILE; tile += 512) {
        const int row  = tile * 64 + wave * 16 + mcol;
        const int rowc = min(row, NN - 1);
        const float* xr = x + (size_t)rowc * NF + quad * 8;

        floatx4 acc[8] = {};
        float4 lo = *(const float4*)(xr);
        float4 hi = *(const float4*)(xr + 4);
#pragma unroll
        for (int ks = 0; ks < 8; ++ks) {
            ABfrag a;
            a.u[0] = pack2bf(lo.x, lo.y);
            a.u[1] = pack2bf(lo.z, lo.w);
            a.u[2] = pack2bf(hi.x, hi.y);
            a.u[3] = pack2bf(hi.z, hi.w);
            if (ks < 7) {
                lo = *(const float4*)(xr + (ks + 1) * 32);
                hi = *(const float4*)(xr + (ks + 1) * 32 + 4);
            }
#pragma unroll
            for (int nt = 0; nt < 8; ++nt) {
                ABfrag b;
                const uint4 bw = sB[(ks * 8 + nt) * 64 + lane];
                b.u[0] = bw.x; b.u[1] = bw.y; b.u[2] = bw.z; b.u[3] = bw.w;
                acc[nt] = __builtin_amdgcn_mfma_f32_16x16x32_bf16(a.s, b.s, acc[nt], 0, 0, 0);
            }
        }
        const int rowbase = tile * 64 + wave * 16 + quad * 4;
#pragma unroll
        for (int nt = 0; nt < 8; ++nt) {
#pragma unroll
            for (int r = 0; r < 4; ++r) {
                const int rr = rowbase + r;
                if (rr < NN) xwh[(size_t)rr * NH + nt * 16 + mcol] = f2bf(acc[nt][r]);
            }
        }
    }
}

// ======================= CSR build: pass 1 histogram ======================
__global__ __launch_bounds__(256) void p1hist_k(const int* __restrict__ edst,
                                                int* __restrict__ hmat) {
    __shared__ uint h[NBUCK];
    for (int i = threadIdx.x; i < NBUCK; i += 256) h[i] = 0;
    __syncthreads();
    const int b = blockIdx.x;
    const int e0 = b * CH, e1 = min(NE, e0 + CH);
    for (int e = e0 + threadIdx.x * 4; e + 3 < e1; e += 1024) {  // (e1-e0) % 4 == 0
        const int4 d4 = *(const int4*)(edst + e);
        atomicAdd(&h[((uint)d4.x) >> 7], 1u);
        atomicAdd(&h[((uint)d4.y) >> 7], 1u);
        atomicAdd(&h[((uint)d4.z) >> 7], 1u);
        atomicAdd(&h[((uint)d4.w) >> 7], 1u);
    }
    __syncthreads();
    for (int i = threadIdx.x; i < NBUCK; i += 256)
        hmat[(size_t)i * NBLK + b] = (int)h[i];
}

// ======================= scan of hmat (306K ints) =========================
__global__ __launch_bounds__(512) void hscan1_k(int* __restrict__ hmat,
                                                int* __restrict__ partials) {
    __shared__ int s[512];
    const int t = threadIdx.x;
    const int i = blockIdx.x * 512 + t;
    const int v = (i < HTOT) ? hmat[i] : 0;
    s[t] = v;
    __syncthreads();
#pragma unroll
    for (int off = 1; off < 512; off <<= 1) {
        int a = (t >= off) ? s[t - off] : 0;
        __syncthreads();
        s[t] += a;
        __syncthreads();
    }
    if (i < HTOT) hmat[i] = s[t] - v;          // exclusive, block-local
    if (t == 511) partials[blockIdx.x] = s[t];
}

__global__ __launch_bounds__(1024) void hscan2_k(int* __restrict__ partials, int nb) {
    __shared__ int s[1024];
    const int t = threadIdx.x;
    const int v = (t < nb) ? partials[t] : 0;
    s[t] = v;
    __syncthreads();
#pragma unroll
    for (int off = 1; off < 1024; off <<= 1) {
        int a = (t >= off) ? s[t - off] : 0;
        __syncthreads();
        s[t] += a;
        __syncthreads();
    }
    if (t < nb) partials[t] = s[t] - v;        // exclusive
}

// ======================= pass 1 scatter (partials folded in) ==============
__global__ __launch_bounds__(256) void p1scat_k(const int* __restrict__ esrc,
                                                const int* __restrict__ edst,
                                                const float* __restrict__ ew,
                                                const int* __restrict__ hmat,
                                                const int* __restrict__ partials,
                                                uint2* __restrict__ ep1) {
    __shared__ uint base[NBUCK];
    const int b = blockIdx.x;
    for (int i = threadIdx.x; i < NBUCK; i += 256) {
        const int g = i * NBLK + b;
        base[i] = (uint)(hmat[g] + partials[g >> 9]);
    }
    __syncthreads();
    const int e0 = b * CH, e1 = min(NE, e0 + CH);
    for (int e = e0 + threadIdx.x; e < e1; e += 256) {
        const uint d = (uint)edst[e];
        const uint pos = atomicAdd(&base[d >> 7], 1u);
        ep1[pos] = make_uint2((uint)esrc[e] | ((d & 127u) << 17), __float_as_uint(ew[e]));
    }
}

// ======================= pass 2: in-bucket sort -> CSR + rp ===============
__global__ __launch_bounds__(256) void p2_k(const int* __restrict__ hmat,
                                            const int* __restrict__ partials,
                                            const uint2* __restrict__ ep1,
                                            uint2* __restrict__ ep,
                                            int* __restrict__ rp) {
    const int bk = blockIdx.x;
    const int gb = bk * NBLK;
    const int beg = hmat[gb] + partials[gb >> 9];
    int end;
    if (bk == NBUCK - 1) end = NE;
    else { const int ge = gb + NBLK; end = hmat[ge] + partials[ge >> 9]; }
    __shared__ uint cnt[128];
    __shared__ uint st[128];
    if (threadIdx.x < 128) cnt[threadIdx.x] = 0;
    __syncthreads();
    for (int j = beg + threadIdx.x; j < end; j += 256)
        atomicAdd(&cnt[(ep1[j].x >> 17) & 127u], 1u);
    __syncthreads();
    if (threadIdx.x < 128) st[threadIdx.x] = cnt[threadIdx.x];
    __syncthreads();
#pragma unroll
    for (int off = 1; off < 128; off <<= 1) {
        uint a = 0;
        if (threadIdx.x < 128 && threadIdx.x >= off) a = st[threadIdx.x - off];
        __syncthreads();
        if (threadIdx.x < 128) st[threadIdx.x] += a;
        __syncthreads();
    }
    if (threadIdx.x < 128) {
        const uint start = st[threadIdx.x] - cnt[threadIdx.x];
        const int d = bk * 128 + threadIdx.x;
        if (d < NN) rp[d] = beg + (int)start;
        cnt[threadIdx.x] = (uint)beg + start;
    }
    if (bk == 0 && threadIdx.x == 200) rp[NN] = NE;
    __syncthreads();
    for (int j = beg + threadIdx.x; j < end; j += 256) {
        const uint2 r = ep1[j];
        const uint pos = atomicAdd(&cnt[(r.x >> 17) & 127u], 1u);
        ep[pos] = r;
    }
}

// ================ SpMM1 + bias + L2norm + ReLU -> bf16 h2 =================
// one wave per node; edge metadata forced to SGPRs via readfirstlane.
__global__ __launch_bounds__(256) void spmm1n_g(const int* __restrict__ rp,
                                                const uint2* __restrict__ ep,
                                                const uint* __restrict__ xwb,
                                                const float* __restrict__ b0,
                                                uint* __restrict__ h2b) {
    const int n = blockIdx.x * 4 + (threadIdx.x >> 6);
    const int t = threadIdx.x & 63;
    const int beg = __builtin_amdgcn_readfirstlane(rp[n]);
    const int end = __builtin_amdgcn_readfirstlane(rp[n + 1]);
    float a0 = 0.f, a1 = 0.f;
    int j = beg;
    for (; j + 7 < end; j += 8) {
        uint sx[8];
        float w[8];
#pragma unroll
        for (int u = 0; u < 8; ++u) {
            const uint2 e = ep[j + u];
            sx[u] = __builtin_amdgcn_readfirstlane(e.x) & 0x1FFFFu;
            w[u]  = __uint_as_float(__builtin_amdgcn_readfirstlane(e.y));
        }
        uint v[8];
#pragma unroll
        for (int u = 0; u < 8; ++u) v[u] = xwb[(size_t)sx[u] * 64 + t];
#pragma unroll
        for (int u = 0; u < 8; ++u) {
            a0 = fmaf(w[u], bflo(v[u]), a0);
            a1 = fmaf(w[u], bfhi(v[u]), a1);
        }
    }
    for (; j < end; ++j) {
        const uint2 e = ep[j];
        const uint sx = __builtin_amdgcn_readfirstlane(e.x) & 0x1FFFFu;
        const float w = __uint_as_float(__builtin_amdgcn_readfirstlane(e.y));
        const uint v = xwb[(size_t)sx * 64 + t];
        a0 = fmaf(w, bflo(v), a0); a1 = fmaf(w, bfhi(v), a1);
    }
    // bias + L2 normalize (wave butterfly) + ReLU, store bf16
    const float2 bb = *(const float2*)(b0 + 2 * t);
    const float v0 = a0 + bb.x, v1 = a1 + bb.y;
    float s = v0 * v0 + v1 * v1;
#pragma unroll
    for (int o = 1; o < 64; o <<= 1) s += __shfl_xor(s, o, 64);
    const float scale = 1.0f / fmaxf(sqrtf(s), 1e-12f);
    h2b[(size_t)n * 64 + t] = pack2bf(fmaxf(v0 * scale, 0.0f), fmaxf(v1 * scale, 0.0f));
}

// ==================== GEMM2 (MFMA bf16, K=128, N=40) ======================
__global__ __launch_bounds__(256) void gemm2_mfma(const uint* __restrict__ h2b,
                                                  const uint4* __restrict__ W1p,
                                                  unsigned short* __restrict__ hwh) {
    __shared__ __align__(16) uint4 sB[768];  // 12 KB: [kstep 0..3][ntile 0..2][lane]
    for (int i = threadIdx.x; i < 768; i += 256) sB[i] = W1p[i];
    __syncthreads();

    const int wave = threadIdx.x >> 6;
    const int lane = threadIdx.x & 63;
    const int quad = lane >> 4;
    const int mcol = lane & 15;
    const int row  = blockIdx.x * 64 + wave * 16 + mcol;
    const int rowc = min(row, NN - 1);
    const uint* hr = h2b + (size_t)rowc * 64;

    floatx4 acc[3] = {};
#pragma unroll
    for (int ks = 0; ks < 4; ++ks) {
        ABfrag a;
        const uint4 hv = *(const uint4*)(hr + ks * 16 + quad * 4);
        a.u[0] = hv.x; a.u[1] = hv.y; a.u[2] = hv.z; a.u[3] = hv.w;
#pragma unroll
        for (int nt = 0; nt < 3; ++nt) {
            ABfrag b;
            const uint4 bw = sB[(ks * 3 + nt) * 64 + lane];
            b.u[0] = bw.x; b.u[1] = bw.y; b.u[2] = bw.z; b.u[3] = bw.w;
            acc[nt] = __builtin_amdgcn_mfma_f32_16x16x32_bf16(a.s, b.s, acc[nt], 0, 0, 0);
        }
    }
    const int rowbase = blockIdx.x * 64 + wave * 16 + quad * 4;
#pragma unroll
    for (int nt = 0; nt < 3; ++nt) {
        const int f = nt * 16 + mcol;
        if (f < NC) {
#pragma unroll
            for (int r = 0; r < 4; ++r) {
                const int rr = rowbase + r;
                if (rr < NN) hwh[(size_t)rr * NC + f] = f2bf(acc[nt][r]);
            }
        }
    }
}

// ============== SpMM2 + bias + log_softmax (fused epilogue) ===============
__global__ __launch_bounds__(320) void spmm2l_g(const int* __restrict__ rp,
                                                const uint2* __restrict__ ep,
                                                const uint* __restrict__ hwb,
                                                const float* __restrict__ b1,
                                                float2* __restrict__ out2) {
    const int nl = threadIdx.x / 20;
    const int g  = threadIdx.x % 20;
    const int n  = blockIdx.x * 16 + nl;
    const int beg = rp[n], end = rp[n + 1];
    float a0 = 0.f, a1 = 0.f;
    int j = beg;
    for (; j + 7 < end; j += 8) {
        uint2 e[8];
        uint v[8];
#pragma unroll
        for (int u = 0; u < 8; ++u) e[u] = ep[j + u];
#pragma unroll
        for (int u = 0; u < 8; ++u) v[u] = hwb[(size_t)(e[u].x & 0x1FFFFu) * 20 + g];
#pragma unroll
        for (int u = 0; u < 8; ++u) {
            const float w = __uint_as_float(e[u].y);
            a0 = fmaf(w, bflo(v[u]), a0);
            a1 = fmaf(w, bfhi(v[u]), a1);
        }
    }
    for (; j < end; ++j) {
        const uint2 e = ep[j];
        const uint v = hwb[(size_t)(e.x & 0x1FFFFu) * 20 + g];
        const float w = __uint_as_float(e.y);
        a0 = fmaf(w, bflo(v), a0); a1 = fmaf(w, bfhi(v), a1);
    }
    const float2 bb = *(const float2*)(b1 + 2 * g);
    a0 += bb.x; a1 += bb.y;
    __shared__ float red[16 * 20];
    __shared__ float stat[16];
    red[nl * 20 + g] = fmaxf(a0, a1);
    __syncthreads();
    if (g == 0) {
        float m = -INFINITY;
#pragma unroll
        for (int q = 0; q < 20; ++q) m = fmaxf(m, red[nl * 20 + q]);
        stat[nl] = m;
    }
    __syncthreads();
    const float m = stat[nl];
    red[nl * 20 + g] = expf(a0 - m) + expf(a1 - m);
    __syncthreads();
    if (g == 0) {
        float ssum = 0.f;
#pragma unroll
        for (int q = 0; q < 20; ++q) ssum += red[nl * 20 + q];
        stat[nl] = logf(ssum);
    }
    __syncthreads();
    const float lse = stat[nl];
    out2[(size_t)n * 20 + g] = make_float2(a0 - m - lse, a1 - m - lse);
}

// ============================ launch ======================================
extern "C" void kernel_launch(void* const* d_in, const int* in_sizes, int n_in,
                              void* d_out, int out_size, void* d_ws, size_t ws_size,
                              hipStream_t stream) {
    const float* x    = (const float*)d_in[0];
    const int*   esrc = (const int*)d_in[1];
    const int*   edst = (const int*)d_in[2];
    const float* ew   = (const float*)d_in[3];
    const float* W0   = (const float*)d_in[4];
    const float* b0   = (const float*)d_in[5];
    const float* W1   = (const float*)d_in[6];
    const float* b1   = (const float*)d_in[7];
    float* out = (float*)d_out;

    // workspace layout (4-byte words); uint2/uint4 arrays at even word offsets.
    size_t o = 0;
    uint*  xwb  = (uint*)d_ws + o;  o += (size_t)NN * 64;         // 25.6 MB
    uint*  h2b  = (uint*)d_ws + o;  o += (size_t)NN * 64;         // 25.6 MB (ep1 aliases)
    uint2* ep1  = (uint2*)h2b;                                    // dead before h2b written
    uint*  hwb  = (uint*)d_ws + o;  o += (size_t)NN * 20;         //  8.0 MB
    uint2* ep   = (uint2*)((uint*)d_ws + o); o += (size_t)NE * 2; // 25.6 MB
    int*   hmat = (int*)d_ws + o;   o += HTOT;                    //  1.2 MB
    int*   rp   = (int*)d_ws + o;   o += NN + 2;
    int*   partials = (int*)d_ws + o; o += 1024;
    if (o & 3) o += 4 - (o & 3);
    uint4* W0p  = (uint4*)((uint*)d_ws + o); o += 16384;          // 64 KB packed W0
    uint4* W1p  = (uint4*)((uint*)d_ws + o); o += 3072;           // 12 KB packed W1

    // 1. pack weights; xw = bf16(x @ W0) via MFMA
    prep_pack_k<<<19, 256, 0, stream>>>(W0, W1, W0p, W1p);
    gemm1_mfma<<<512, 256, 0, stream>>>(x, W0p, (unsigned short*)xwb);

    // 2. CSR build: two-pass counting sort, block-private write ranges
    p1hist_k<<<NBLK, 256, 0, stream>>>(edst, hmat);
    hscan1_k<<<HS1, 512, 0, stream>>>(hmat, partials);
    hscan2_k<<<1, 1024, 0, stream>>>(partials, HS1);
    p1scat_k<<<NBLK, 256, 0, stream>>>(esrc, edst, ew, hmat, partials, ep1);
    p2_k<<<NBUCK, 256, 0, stream>>>(hmat, partials, ep1, ep, rp);

    // 3. h2 = relu(l2norm(spmm(xw) + b0)) as bf16   (overwrites ep1 — dead)
    spmm1n_g<<<NN / 4, 256, 0, stream>>>(rp, ep, xwb, b0, h2b);
    // 4. hw = bf16(h2 @ W1) via MFMA
    gemm2_mfma<<<NTILE, 256, 0, stream>>>(h2b, W1p, (unsigned short*)hwb);
    // 5. out = log_softmax(spmm(hw) + b1)
    spmm2l_g<<<NN / 16, 320, 0, stream>>>(rp, ep, hwb, b1, (float2*)out);
}